// Round 3
// baseline (3136.487 us; speedup 1.0000x reference)
//
#include <hip/hip_runtime.h>

#define NN 100000
#define NE 1600000
#define BN_EPS 1e-5f
#define BSHIFT 5
#define NBK (NN >> BSHIFT)          // 3125 buckets of exactly 32 nodes
#define NBG (NBK * 8)               // 25000 (bucket,group) sub-lists
#define CHUNK 2048                  // edges per scatter block

__constant__ float c_wtab[26] = {0.7f,0.9f,0.7f,0.9f,0.3f,0.7f,0.3f,0.9f,0.3f,0.3f,0.9f,0.7f,0.1f,
                                 0.9f,0.5f,0.9f,0.5f,0.5f,0.1f,0.3f,0.7f,0.9f,0.9f,0.9f,0.9f,0.9f};

__device__ __forceinline__ unsigned f2bf(float f){
    unsigned u = __float_as_uint(f);
    return (u + 0x7fffu + ((u >> 16) & 1u)) >> 16;   // round-to-nearest-even
}
__device__ __forceinline__ float bflo(unsigned v){ return __uint_as_float(v << 16); }
__device__ __forceinline__ float bfhi(unsigned v){ return __uint_as_float(v & 0xffff0000u); }

// ---------------- degree + (bucket,group) histograms ----------------
__global__ void k_hist(const int* __restrict__ src, const int* __restrict__ dst,
                       unsigned* __restrict__ dego, unsigned* __restrict__ degi,
                       unsigned* __restrict__ bgc){
    int e = blockIdx.x*blockDim.x + threadIdx.x;
    if (e < NE){
        int s = src[e], d = dst[e];
        atomicAdd(&dego[s], 1u);
        atomicAdd(&degi[d], 1u);
        int g = (e / CHUNK) & 7;
        atomicAdd(&bgc[(unsigned)(d >> BSHIFT)*8u + (unsigned)g], 1u);
    }
}

// ---------------- per-node: norms + argmax weight + xn0 = h*nsrc (padded [N,32]) ----------------
__global__ void k_node(const float* __restrict__ h, const unsigned* __restrict__ dego,
                       const unsigned* __restrict__ degi, float* __restrict__ nsrc,
                       float* __restrict__ ndst, float* __restrict__ outw,
                       float* __restrict__ xn0){
    int i = blockIdx.x*blockDim.x + threadIdx.x;
    if (i < NN){
        float d0 = (float)dego[i]; d0 = d0 < 1.f ? 1.f : d0;
        float d1 = (float)degi[i]; d1 = d1 < 1.f ? 1.f : d1;
        float ns = rsqrtf(d0);
        nsrc[i] = ns;
        ndst[i] = rsqrtf(d1);
        float row[26];
        #pragma unroll
        for (int c = 0; c < 26; ++c) row[c] = h[(size_t)i*26 + c];
        float best = row[0]; int bi = 0;
        #pragma unroll
        for (int c = 1; c < 26; ++c){ if (row[c] > best){ best = row[c]; bi = c; } }
        outw[i] = c_wtab[bi];
        #pragma unroll
        for (int c = 0; c < 26; ++c) xn0[(size_t)i*32 + c] = row[c]*ns;
    }
}

// ---------------- generic two-level exclusive scan ----------------
__global__ void k_scan1(const unsigned* __restrict__ deg, unsigned* __restrict__ bsums, int n){
    __shared__ unsigned s[512];
    int i = blockIdx.x*512 + threadIdx.x;
    s[threadIdx.x] = (i < n) ? deg[i] : 0u;
    __syncthreads();
    for (int o = 256; o > 0; o >>= 1){
        if (threadIdx.x < o) s[threadIdx.x] += s[threadIdx.x + o];
        __syncthreads();
    }
    if (threadIdx.x == 0) bsums[blockIdx.x] = s[0];
}

__global__ void k_scan2(unsigned* __restrict__ bsums, unsigned* __restrict__ offsets,
                        int nb, int n, unsigned total){
    __shared__ unsigned s[512];
    int t = threadIdx.x;
    unsigned v = (t < nb) ? bsums[t] : 0u;
    s[t] = v; __syncthreads();
    for (int o = 1; o < 512; o <<= 1){
        unsigned x = (t >= o) ? s[t - o] : 0u;
        __syncthreads();
        s[t] += x;
        __syncthreads();
    }
    if (t < nb) bsums[t] = s[t] - v;   // exclusive
    if (t == 0) offsets[n] = total;
}

__global__ void k_scan3(const unsigned* __restrict__ deg, const unsigned* __restrict__ bsums,
                        unsigned* __restrict__ offsets, unsigned* __restrict__ cursor, int n){
    __shared__ unsigned s[512];
    int i = blockIdx.x*512 + threadIdx.x;
    unsigned v = (i < n) ? deg[i] : 0u;
    s[threadIdx.x] = v; __syncthreads();
    for (int o = 1; o < 512; o <<= 1){
        unsigned x = (threadIdx.x >= o) ? s[threadIdx.x - o] : 0u;
        __syncthreads();
        s[threadIdx.x] += x;
        __syncthreads();
    }
    if (i < n){
        unsigned e = bsums[blockIdx.x] + s[threadIdx.x] - v;  // exclusive prefix
        offsets[i] = e;
        cursor[i]  = e;
    }
}

// ---------------- scatter packed (dstLocal,src) into (bucket,group) sub-lists ----------------
__global__ __launch_bounds__(256) void k_bucket(const int* __restrict__ src,
                                                const int* __restrict__ dst,
                                                unsigned* __restrict__ cur,
                                                unsigned* __restrict__ pairs){
    int b = blockIdx.x;
    unsigned g = (unsigned)(b & 7);
    int base = b*CHUNK;
    #pragma unroll
    for (int k = 0; k < CHUNK/256; ++k){
        int e = base + k*256 + threadIdx.x;
        if (e < NE){
            int d = dst[e], s = src[e];
            unsigned p = atomicAdd(&cur[(unsigned)(d >> BSHIFT)*8u + g], 1u);
            pairs[p] = ((unsigned)(d & 31) << 17) | (unsigned)s;
        }
    }
}

// ---------------- layer-0 aggregation: fp32 [N,32]-padded, LDS accumulate ----------------
__global__ __launch_bounds__(256) void k_agg0(const float* __restrict__ xn,
                                              const unsigned* __restrict__ bgoff,
                                              const unsigned* __restrict__ pairs,
                                              float* __restrict__ agg){
    __shared__ float acc[32][32];
    int tid = threadIdx.x;
    for (int i = tid; i < 32*32; i += 256) (&acc[0][0])[i] = 0.f;
    __syncthreads();
    int b = blockIdx.x;
    unsigned beg = bgoff[b*8], end = bgoff[b*8 + 8];
    int lane = tid & 63, w = tid >> 6;
    int sub = lane >> 5, ch = lane & 31;
    for (unsigned e = beg + (unsigned)(w*2 + sub); e < end; e += 8){
        unsigned pr = pairs[e];
        unsigned s = pr & 0x1FFFFu, dl = pr >> 17;
        if (ch < 26){
            float v = xn[(size_t)s*32 + ch];
            atomicAdd(&acc[dl][ch], v);
        }
    }
    __syncthreads();
    int node0 = b << BSHIFT;
    for (int i = tid; i < 256; i += 256){   // 32 nodes * 8 float4 = 256
        int dl = i >> 3, q = i & 7;
        reinterpret_cast<float4*>(agg + (size_t)(node0 + dl)*32)[q] =
            reinterpret_cast<float4*>(&acc[dl][0])[q];
    }
}

// ---------------- layers 1/2 aggregation: bf16 gather, LDS accumulate ----------------
__global__ __launch_bounds__(256) void k_agg_bf(const unsigned* __restrict__ xn,
                                                const unsigned* __restrict__ bgoff,
                                                const unsigned* __restrict__ pairs,
                                                float* __restrict__ agg){
    __shared__ float acc[32][128];
    int tid = threadIdx.x;
    for (int i = tid; i < 32*128; i += 256) (&acc[0][0])[i] = 0.f;
    __syncthreads();
    int b = blockIdx.x;
    unsigned beg = bgoff[b*8], end = bgoff[b*8 + 8];
    int lane = tid & 63, w = tid >> 6;
    for (unsigned e = beg + (unsigned)w; e < end; e += 4){
        unsigned pr = pairs[e];
        unsigned s = pr & 0x1FFFFu, dl = pr >> 17;
        unsigned v = xn[(size_t)s*64 + lane];     // dword lane = (ch lane | ch lane+64)
        atomicAdd(&acc[dl][lane],      bflo(v));
        atomicAdd(&acc[dl][lane + 64], bfhi(v));
    }
    __syncthreads();
    int node0 = b << BSHIFT;
    for (int i = tid; i < 1024; i += 256){  // 32 nodes * 32 float4
        int dl = i >> 5, q = i & 31;
        reinterpret_cast<float4*>(agg + (size_t)(node0 + dl)*128)[q] =
            reinterpret_cast<float4*>(&acc[dl][0])[q];
    }
}

// ---------------- GEMM: Z = A @ W (*ndst) + bias, optional fused BN stats ----------------
template<int CIN, int COUT, int LDA, bool STATS>
__global__ __launch_bounds__(256) void k_gemm(const float* __restrict__ A,
                                              const float* __restrict__ W,
                                              const float* __restrict__ bias,
                                              const float* __restrict__ ndst,
                                              float* __restrict__ Z,
                                              float* __restrict__ stats){
    constexpr int ROWS = 64;
    constexpr int KC = 32;
    constexpr int CG = COUT / 8;          // col groups of 8
    constexpr int TPB = 256;
    constexpr int RPT = ROWS * CG / TPB;  // rows per thread
    __shared__ float sW[KC][COUT];
    __shared__ float sA[ROWS][KC + 1];
    __shared__ float sS[2][COUT];
    const int tid = threadIdx.x;
    const int cg  = tid % CG;
    const int rg  = tid / CG;
    const int row0 = blockIdx.x * ROWS;
    float acc[RPT][8];
    #pragma unroll
    for (int r = 0; r < RPT; ++r)
        #pragma unroll
        for (int c = 0; c < 8; ++c) acc[r][c] = 0.f;

    for (int k0 = 0; k0 < CIN; k0 += KC){
        const int kc = (CIN - k0) < KC ? (CIN - k0) : KC;
        for (int idx = tid; idx < kc*COUT; idx += TPB){
            int kk = idx / COUT, c = idx - kk*COUT;
            sW[kk][c] = W[(k0 + kk)*COUT + c];
        }
        for (int idx = tid; idx < ROWS*kc; idx += TPB){
            int r = idx / kc, kk = idx - r*kc;
            int gr = row0 + r;
            sA[r][kk] = (gr < NN) ? A[(size_t)gr*LDA + k0 + kk] : 0.f;
        }
        __syncthreads();
        for (int kk = 0; kk < kc; ++kk){
            float w[8];
            #pragma unroll
            for (int c = 0; c < 8; ++c) w[c] = sW[kk][cg*8 + c];
            #pragma unroll
            for (int r = 0; r < RPT; ++r){
                float a = sA[rg*RPT + r][kk];
                #pragma unroll
                for (int c = 0; c < 8; ++c) acc[r][c] += a * w[c];
            }
        }
        __syncthreads();
    }
    if (STATS){
        for (int i = tid; i < 2*COUT; i += TPB) (&sS[0][0])[i] = 0.f;
    }
    __syncthreads();
    float cs[8], cq[8];
    #pragma unroll
    for (int c = 0; c < 8; ++c){ cs[c] = 0.f; cq[c] = 0.f; }
    #pragma unroll
    for (int r = 0; r < RPT; ++r){
        int gr = row0 + rg*RPT + r;
        if (gr < NN){
            float nm = ndst ? ndst[gr] : 1.f;
            float z[8];
            #pragma unroll
            for (int c = 0; c < 8; ++c){
                z[c] = acc[r][c]*nm + bias[cg*8 + c];
                if (STATS){ cs[c] += z[c]; cq[c] += z[c]*z[c]; }
            }
            float* zp = &Z[(size_t)gr*COUT + cg*8];
            reinterpret_cast<float4*>(zp)[0] = make_float4(z[0], z[1], z[2], z[3]);
            reinterpret_cast<float4*>(zp)[1] = make_float4(z[4], z[5], z[6], z[7]);
        }
    }
    if (STATS){
        #pragma unroll
        for (int c = 0; c < 8; ++c){
            atomicAdd(&sS[0][cg*8 + c], cs[c]);
            atomicAdd(&sS[1][cg*8 + c], cq[c]);
        }
        __syncthreads();
        for (int i = tid; i < COUT; i += TPB){
            atomicAdd(&stats[i],        sS[0][i]);
            atomicAdd(&stats[128 + i],  sS[1][i]);
        }
    }
}

// ---------------- BN finalize: scale/shift ----------------
__global__ void k_bnfin(float* __restrict__ stats, const float* __restrict__ g,
                        const float* __restrict__ bt){
    int c = threadIdx.x;  // 128
    float mu  = stats[c] / (float)NN;
    float var = stats[128 + c] / (float)NN - mu*mu;
    if (var < 0.f) var = 0.f;
    float sc = g[c] * rsqrtf(var + BN_EPS);
    stats[256 + c] = sc;
    stats[384 + c] = bt[c] - mu*sc;
}

// ---------------- BN apply + ReLU + *nsrc -> bf16, dword d = (ch d | ch d+64) ----------------
__global__ void k_bnapply_bf(const float* __restrict__ X, const float* __restrict__ stats,
                             const float* __restrict__ nsrc, unsigned* __restrict__ out){
    int idx = blockIdx.x*blockDim.x + threadIdx.x;
    if (idx < NN*64){
        int d = idx & 63;
        int node = idx >> 6;
        float ns = nsrc[node];
        float x0 = X[(size_t)node*128 + d];
        float x1 = X[(size_t)node*128 + d + 64];
        float v0 = x0*stats[256 + d]      + stats[384 + d];
        float v1 = x1*stats[256 + d + 64] + stats[384 + d + 64];
        v0 = v0 > 0.f ? v0*ns : 0.f;
        v1 = v1 > 0.f ? v1*ns : 0.f;
        out[idx] = f2bf(v0) | (f2bf(v1) << 16);
    }
}

// ---------------- BN apply + ReLU, fp32 in place (layer 2) ----------------
__global__ void k_bnapply_f32(float* __restrict__ X, const float* __restrict__ stats){
    int idx = blockIdx.x*blockDim.x + threadIdx.x;
    const int total = NN * 128;
    if (idx < total){
        int c = idx & 127;
        float v = X[idx]*stats[256 + c] + stats[384 + c];
        X[idx] = v > 0.f ? v : 0.f;
    }
}

extern "C" void kernel_launch(void* const* d_in, const int* in_sizes, int n_in,
                              void* d_out, int out_size, void* d_ws, size_t ws_size,
                              hipStream_t stream) {
    const float* h   = (const float*)d_in[0];
    const int*   src = (const int*)d_in[1];
    const int*   dst = (const int*)d_in[2];
    const float* w0  = (const float*)d_in[3];
    const float* b0  = (const float*)d_in[4];
    const float* w1  = (const float*)d_in[5];
    const float* b1  = (const float*)d_in[6];
    const float* w2  = (const float*)d_in[7];
    const float* b2  = (const float*)d_in[8];
    const float* g0  = (const float*)d_in[9];
    const float* bt0 = (const float*)d_in[10];
    const float* g1  = (const float*)d_in[11];
    const float* bt1 = (const float*)d_in[12];
    const float* g2  = (const float*)d_in[13];
    const float* bt2 = (const float*)d_in[14];
    const float* wfc = (const float*)d_in[15];
    const float* bfc = (const float*)d_in[16];

    float* out   = (float*)d_out;                     // [NN,64]
    float* out_w = out + (size_t)NN*64;               // [NN,1]

    char* ws = (char*)d_ws;
    size_t off = 0;
    auto alloc = [&](size_t b){ size_t p = off; off += (b + 255) & ~(size_t)255; return ws + p; };

    unsigned* dego   = (unsigned*)alloc((size_t)NN*4);
    unsigned* degi   = (unsigned*)alloc((size_t)NN*4);
    float*    nsrc   = (float*)   alloc((size_t)NN*4);
    float*    ndst   = (float*)   alloc((size_t)NN*4);
    unsigned* bgc    = (unsigned*)alloc((size_t)NBG*4);        // (bucket,group) counts
    unsigned* bgoff  = (unsigned*)alloc((size_t)(NBG+1)*4);    // scanned offsets
    unsigned* bgcur  = (unsigned*)alloc((size_t)NBG*4);        // scatter cursors
    unsigned* bsums  = (unsigned*)alloc(512*4);
    float*    stats  = (float*)   alloc(3*512*4);   // per layer: [sum|sumsq|scale|shift] x128
    unsigned* pairs  = (unsigned*)alloc((size_t)NE*4);         // packed (dl<<17 | src)
    float*    xn0    = (float*)   alloc((size_t)NN*32*4);      // h*nsrc padded
    float*    bufA   = (float*)   alloc((size_t)NN*128*4);     // GEMM out
    float*    bufB   = (float*)   alloc((size_t)NN*128*4);     // agg out
    unsigned* bufC   = (unsigned*)alloc((size_t)NN*64*4);      // bf16 features
    (void)ws_size; (void)in_sizes; (void)n_in; (void)out_size;

    hipMemsetAsync(dego, 0, (size_t)NN*4, stream);
    hipMemsetAsync(degi, 0, (size_t)NN*4, stream);
    hipMemsetAsync(bgc,  0, (size_t)NBG*4, stream);
    hipMemsetAsync(stats, 0, 3*512*4, stream);

    const int NB2 = (NBG + 511) / 512;   // 49 scan blocks

    k_hist<<<(NE + 255)/256, 256, 0, stream>>>(src, dst, dego, degi, bgc);
    k_node<<<(NN + 255)/256, 256, 0, stream>>>(h, dego, degi, nsrc, ndst, out_w, xn0);
    k_scan1<<<NB2, 512, 0, stream>>>(bgc, bsums, NBG);
    k_scan2<<<1, 512, 0, stream>>>(bsums, bgoff, NB2, NBG, (unsigned)NE);
    k_scan3<<<NB2, 512, 0, stream>>>(bgc, bsums, bgoff, bgcur, NBG);
    k_bucket<<<(NE + CHUNK - 1)/CHUNK, 256, 0, stream>>>(src, dst, bgcur, pairs);

    // ---- layer 0: agg26 -> gemm 26x128 (+stats) -> bnfin -> apply->bf16 ----
    k_agg0<<<NBK, 256, 0, stream>>>(xn0, bgoff, pairs, bufB);
    k_gemm<26,128,32,true><<<(NN + 63)/64, 256, 0, stream>>>(bufB, w0, b0, ndst, bufA, stats + 0*512);
    k_bnfin<<<1, 128, 0, stream>>>(stats + 0*512, g0, bt0);
    k_bnapply_bf<<<(NN*64 + 255)/256, 256, 0, stream>>>(bufA, stats + 0*512, nsrc, bufC);

    // ---- layer 1 ----
    k_agg_bf<<<NBK, 256, 0, stream>>>(bufC, bgoff, pairs, bufB);
    k_gemm<128,128,128,true><<<(NN + 63)/64, 256, 0, stream>>>(bufB, w1, b1, ndst, bufA, stats + 1*512);
    k_bnfin<<<1, 128, 0, stream>>>(stats + 1*512, g1, bt1);
    k_bnapply_bf<<<(NN*64 + 255)/256, 256, 0, stream>>>(bufA, stats + 1*512, nsrc, bufC);

    // ---- layer 2 ----
    k_agg_bf<<<NBK, 256, 0, stream>>>(bufC, bgoff, pairs, bufB);
    k_gemm<128,128,128,true><<<(NN + 63)/64, 256, 0, stream>>>(bufB, w2, b2, ndst, bufA, stats + 2*512);
    k_bnfin<<<1, 128, 0, stream>>>(stats + 2*512, g2, bt2);
    k_bnapply_f32<<<(NN*128 + 255)/256, 256, 0, stream>>>(bufA, stats + 2*512);

    // ---- FC: out = x @ wfc + bfc ----
    k_gemm<128,64,128,false><<<(NN + 63)/64, 256, 0, stream>>>(bufA, wfc, bfc, nullptr, out, nullptr);
}

// Round 4
// 941.145 us; speedup vs baseline: 3.3326x; 3.3326x over previous
//
#include <hip/hip_runtime.h>

#define NN 100000
#define NE 1600000
#define BN_EPS 1e-5f
#define BSHIFT 5
#define NBK (NN >> BSHIFT)          // 3125 buckets of exactly 32 nodes
#define NBG (NBK * 8)               // 25000 (bucket,group) sub-lists
#define CHUNK 2048                  // edges per scatter block

__constant__ float c_wtab[26] = {0.7f,0.9f,0.7f,0.9f,0.3f,0.7f,0.3f,0.9f,0.3f,0.3f,0.9f,0.7f,0.1f,
                                 0.9f,0.5f,0.9f,0.5f,0.5f,0.1f,0.3f,0.7f,0.9f,0.9f,0.9f,0.9f,0.9f};

__device__ __forceinline__ unsigned f2bf(float f){
    unsigned u = __float_as_uint(f);
    return (u + 0x7fffu + ((u >> 16) & 1u)) >> 16;   // round-to-nearest-even
}
__device__ __forceinline__ float bflo(unsigned v){ return __uint_as_float(v << 16); }
__device__ __forceinline__ float bfhi(unsigned v){ return __uint_as_float(v & 0xffff0000u); }

// ---------------- degree + (bucket,group) histograms ----------------
__global__ void k_hist(const int* __restrict__ src, const int* __restrict__ dst,
                       unsigned* __restrict__ dego, unsigned* __restrict__ degi,
                       unsigned* __restrict__ bgc){
    int e = blockIdx.x*blockDim.x + threadIdx.x;
    if (e < NE){
        int s = src[e], d = dst[e];
        atomicAdd(&dego[s], 1u);
        atomicAdd(&degi[d], 1u);
        int g = (e / CHUNK) & 7;
        atomicAdd(&bgc[(unsigned)(d >> BSHIFT)*8u + (unsigned)g], 1u);
    }
}

// ---------------- per-node: norms + argmax weight + xn0 = h*nsrc (padded [N,32]) ----------------
__global__ void k_node(const float* __restrict__ h, const unsigned* __restrict__ dego,
                       const unsigned* __restrict__ degi, float* __restrict__ nsrc,
                       float* __restrict__ ndst, float* __restrict__ outw,
                       float* __restrict__ xn0){
    int i = blockIdx.x*blockDim.x + threadIdx.x;
    if (i < NN){
        float d0 = (float)dego[i]; d0 = d0 < 1.f ? 1.f : d0;
        float d1 = (float)degi[i]; d1 = d1 < 1.f ? 1.f : d1;
        float ns = rsqrtf(d0);
        nsrc[i] = ns;
        ndst[i] = rsqrtf(d1);
        float row[26];
        #pragma unroll
        for (int c = 0; c < 26; ++c) row[c] = h[(size_t)i*26 + c];
        float best = row[0]; int bi = 0;
        #pragma unroll
        for (int c = 1; c < 26; ++c){ if (row[c] > best){ best = row[c]; bi = c; } }
        outw[i] = c_wtab[bi];
        #pragma unroll
        for (int c = 0; c < 26; ++c) xn0[(size_t)i*32 + c] = row[c]*ns;
        #pragma unroll
        for (int c = 26; c < 32; ++c) xn0[(size_t)i*32 + c] = 0.f;
    }
}

// ---------------- generic two-level exclusive scan ----------------
__global__ void k_scan1(const unsigned* __restrict__ deg, unsigned* __restrict__ bsums, int n){
    __shared__ unsigned s[512];
    int i = blockIdx.x*512 + threadIdx.x;
    s[threadIdx.x] = (i < n) ? deg[i] : 0u;
    __syncthreads();
    for (int o = 256; o > 0; o >>= 1){
        if (threadIdx.x < o) s[threadIdx.x] += s[threadIdx.x + o];
        __syncthreads();
    }
    if (threadIdx.x == 0) bsums[blockIdx.x] = s[0];
}

__global__ void k_scan2(unsigned* __restrict__ bsums, unsigned* __restrict__ offsets,
                        int nb, int n, unsigned total){
    __shared__ unsigned s[512];
    int t = threadIdx.x;
    unsigned v = (t < nb) ? bsums[t] : 0u;
    s[t] = v; __syncthreads();
    for (int o = 1; o < 512; o <<= 1){
        unsigned x = (t >= o) ? s[t - o] : 0u;
        __syncthreads();
        s[t] += x;
        __syncthreads();
    }
    if (t < nb) bsums[t] = s[t] - v;   // exclusive
    if (t == 0) offsets[n] = total;
}

__global__ void k_scan3(const unsigned* __restrict__ deg, const unsigned* __restrict__ bsums,
                        unsigned* __restrict__ offsets, unsigned* __restrict__ cursor, int n){
    __shared__ unsigned s[512];
    int i = blockIdx.x*512 + threadIdx.x;
    unsigned v = (i < n) ? deg[i] : 0u;
    s[threadIdx.x] = v; __syncthreads();
    for (int o = 1; o < 512; o <<= 1){
        unsigned x = (threadIdx.x >= o) ? s[threadIdx.x - o] : 0u;
        __syncthreads();
        s[threadIdx.x] += x;
        __syncthreads();
    }
    if (i < n){
        unsigned e = bsums[blockIdx.x] + s[threadIdx.x] - v;  // exclusive prefix
        offsets[i] = e;
        cursor[i]  = e;
    }
}

// ---------------- scatter packed (dstLocal,src) into (bucket,group) sub-lists ----------------
__global__ __launch_bounds__(256) void k_bucket(const int* __restrict__ src,
                                                const int* __restrict__ dst,
                                                unsigned* __restrict__ cur,
                                                unsigned* __restrict__ pairs){
    int b = blockIdx.x;
    unsigned g = (unsigned)(b & 7);
    int base = b*CHUNK;
    #pragma unroll
    for (int k = 0; k < CHUNK/256; ++k){
        int e = base + k*256 + threadIdx.x;
        if (e < NE){
            int d = dst[e], s = src[e];
            unsigned p = atomicAdd(&cur[(unsigned)(d >> BSHIFT)*8u + g], 1u);
            pairs[p] = ((unsigned)(d & 31) << 17) | (unsigned)s;
        }
    }
}

// ---------------- within-bucket scatter to exact CSR position ----------------
__global__ __launch_bounds__(256) void k_fill2(const unsigned* __restrict__ bgoff,
                                               const unsigned* __restrict__ pairs,
                                               unsigned* __restrict__ cursor,
                                               int* __restrict__ csr){
    int b = blockIdx.x;
    unsigned beg = bgoff[b*8], end = bgoff[b*8 + 8];
    int node0 = b << BSHIFT;
    for (unsigned e = beg + threadIdx.x; e < end; e += 256){
        unsigned pr = pairs[e];
        unsigned p = atomicAdd(&cursor[node0 + (pr >> 17)], 1u);
        csr[p] = (int)(pr & 0x1FFFFu);
    }
}

// ---------------- layer-0 aggregation: fp32 [N,32]-padded, 2 nodes per wave ----------------
__global__ __launch_bounds__(64) void k_agg0(const float* __restrict__ xn,
                                             const unsigned* __restrict__ offs,
                                             const int* __restrict__ csr,
                                             float* __restrict__ agg){
    int node = blockIdx.x*2 + (threadIdx.x >> 5);
    int c = threadIdx.x & 31;
    unsigned beg = offs[node], end = offs[node + 1];
    float acc = 0.f;
    unsigned e = beg;
    for (; e + 4 <= end; e += 4){
        int s0 = csr[e+0], s1 = csr[e+1], s2 = csr[e+2], s3 = csr[e+3];
        float a0 = xn[(size_t)s0*32 + c];
        float a1 = xn[(size_t)s1*32 + c];
        float a2 = xn[(size_t)s2*32 + c];
        float a3 = xn[(size_t)s3*32 + c];
        acc += (a0 + a1) + (a2 + a3);
    }
    for (; e < end; ++e)
        acc += xn[(size_t)csr[e]*32 + c];
    agg[(size_t)node*32 + c] = acc;
}

// ---------------- layers 1/2 aggregation: bf16 gather, register accumulate, 8-unroll ----------------
__global__ __launch_bounds__(64) void k_agg_bf(const unsigned* __restrict__ xn,
                                               const unsigned* __restrict__ offs,
                                               const int* __restrict__ csr,
                                               float* __restrict__ agg){
    int node = blockIdx.x;
    int t = threadIdx.x;   // dword t = channels (2t, 2t+1)
    unsigned beg = offs[node], end = offs[node + 1];
    float a0 = 0.f, a1 = 0.f;
    unsigned e = beg;
    for (; e + 8 <= end; e += 8){
        int s[8];
        #pragma unroll
        for (int i = 0; i < 8; ++i) s[i] = csr[e + i];
        #pragma unroll
        for (int i = 0; i < 8; ++i){
            unsigned v = xn[(size_t)s[i]*64 + t];
            a0 += bflo(v);
            a1 += bfhi(v);
        }
    }
    for (; e < end; ++e){
        unsigned v = xn[(size_t)csr[e]*64 + t];
        a0 += bflo(v);
        a1 += bfhi(v);
    }
    reinterpret_cast<float2*>(agg + (size_t)node*128)[t] = make_float2(a0, a1);
}

// ---------------- GEMM: Z = A @ W (*ndst) + bias, optional fused BN stats ----------------
template<int CIN, int COUT, int LDA, bool STATS>
__global__ __launch_bounds__(256) void k_gemm(const float* __restrict__ A,
                                              const float* __restrict__ W,
                                              const float* __restrict__ bias,
                                              const float* __restrict__ ndst,
                                              float* __restrict__ Z,
                                              float* __restrict__ stats){
    constexpr int ROWS = 64;
    constexpr int KC = 32;
    constexpr int CG = COUT / 8;          // col groups of 8
    constexpr int TPB = 256;
    constexpr int RPT = ROWS * CG / TPB;  // rows per thread
    __shared__ float sW[KC][COUT];
    __shared__ float sA[ROWS][KC + 1];
    __shared__ float sS[2][COUT];
    const int tid = threadIdx.x;
    const int cg  = tid % CG;
    const int rg  = tid / CG;
    const int row0 = blockIdx.x * ROWS;
    float acc[RPT][8];
    #pragma unroll
    for (int r = 0; r < RPT; ++r)
        #pragma unroll
        for (int c = 0; c < 8; ++c) acc[r][c] = 0.f;

    for (int k0 = 0; k0 < CIN; k0 += KC){
        const int kc = (CIN - k0) < KC ? (CIN - k0) : KC;
        for (int idx = tid; idx < kc*COUT; idx += TPB){
            int kk = idx / COUT, c = idx - kk*COUT;
            sW[kk][c] = W[(k0 + kk)*COUT + c];
        }
        for (int idx = tid; idx < ROWS*kc; idx += TPB){
            int r = idx / kc, kk = idx - r*kc;
            int gr = row0 + r;
            sA[r][kk] = (gr < NN) ? A[(size_t)gr*LDA + k0 + kk] : 0.f;
        }
        __syncthreads();
        for (int kk = 0; kk < kc; ++kk){
            float w[8];
            #pragma unroll
            for (int c = 0; c < 8; ++c) w[c] = sW[kk][cg*8 + c];
            #pragma unroll
            for (int r = 0; r < RPT; ++r){
                float a = sA[rg*RPT + r][kk];
                #pragma unroll
                for (int c = 0; c < 8; ++c) acc[r][c] += a * w[c];
            }
        }
        __syncthreads();
    }
    if (STATS){
        for (int i = tid; i < 2*COUT; i += TPB) (&sS[0][0])[i] = 0.f;
    }
    __syncthreads();
    float cs[8], cq[8];
    #pragma unroll
    for (int c = 0; c < 8; ++c){ cs[c] = 0.f; cq[c] = 0.f; }
    #pragma unroll
    for (int r = 0; r < RPT; ++r){
        int gr = row0 + rg*RPT + r;
        if (gr < NN){
            float nm = ndst ? ndst[gr] : 1.f;
            float z[8];
            #pragma unroll
            for (int c = 0; c < 8; ++c){
                z[c] = acc[r][c]*nm + bias[cg*8 + c];
                if (STATS){ cs[c] += z[c]; cq[c] += z[c]*z[c]; }
            }
            float* zp = &Z[(size_t)gr*COUT + cg*8];
            reinterpret_cast<float4*>(zp)[0] = make_float4(z[0], z[1], z[2], z[3]);
            reinterpret_cast<float4*>(zp)[1] = make_float4(z[4], z[5], z[6], z[7]);
        }
    }
    if (STATS){
        #pragma unroll
        for (int c = 0; c < 8; ++c){
            atomicAdd(&sS[0][cg*8 + c], cs[c]);
            atomicAdd(&sS[1][cg*8 + c], cq[c]);
        }
        __syncthreads();
        for (int i = tid; i < COUT; i += TPB){
            atomicAdd(&stats[i],        sS[0][i]);
            atomicAdd(&stats[128 + i],  sS[1][i]);
        }
    }
}

// ---------------- BN finalize: scale/shift ----------------
__global__ void k_bnfin(float* __restrict__ stats, const float* __restrict__ g,
                        const float* __restrict__ bt){
    int c = threadIdx.x;  // 128
    float mu  = stats[c] / (float)NN;
    float var = stats[128 + c] / (float)NN - mu*mu;
    if (var < 0.f) var = 0.f;
    float sc = g[c] * rsqrtf(var + BN_EPS);
    stats[256 + c] = sc;
    stats[384 + c] = bt[c] - mu*sc;
}

// ---------------- BN apply + ReLU + *nsrc -> bf16, dword d = (ch 2d, ch 2d+1) ----------------
__global__ void k_bnapply_bf(const float* __restrict__ X, const float* __restrict__ stats,
                             const float* __restrict__ nsrc, unsigned* __restrict__ out){
    int idx = blockIdx.x*blockDim.x + threadIdx.x;
    if (idx < NN*64){
        int d = idx & 63;
        int node = idx >> 6;
        int c0 = d << 1;
        float2 x = reinterpret_cast<const float2*>(X)[idx];
        float ns = nsrc[node];
        float v0 = x.x*stats[256 + c0]     + stats[384 + c0];
        float v1 = x.y*stats[256 + c0 + 1] + stats[384 + c0 + 1];
        v0 = v0 > 0.f ? v0*ns : 0.f;
        v1 = v1 > 0.f ? v1*ns : 0.f;
        out[idx] = f2bf(v0) | (f2bf(v1) << 16);
    }
}

// ---------------- BN apply + ReLU, fp32 in place (layer 2) ----------------
__global__ void k_bnapply_f32(float* __restrict__ X, const float* __restrict__ stats){
    int idx = blockIdx.x*blockDim.x + threadIdx.x;
    const int total = NN * 128;
    if (idx < total){
        int c = idx & 127;
        float v = X[idx]*stats[256 + c] + stats[384 + c];
        X[idx] = v > 0.f ? v : 0.f;
    }
}

extern "C" void kernel_launch(void* const* d_in, const int* in_sizes, int n_in,
                              void* d_out, int out_size, void* d_ws, size_t ws_size,
                              hipStream_t stream) {
    const float* h   = (const float*)d_in[0];
    const int*   src = (const int*)d_in[1];
    const int*   dst = (const int*)d_in[2];
    const float* w0  = (const float*)d_in[3];
    const float* b0  = (const float*)d_in[4];
    const float* w1  = (const float*)d_in[5];
    const float* b1  = (const float*)d_in[6];
    const float* w2  = (const float*)d_in[7];
    const float* b2  = (const float*)d_in[8];
    const float* g0  = (const float*)d_in[9];
    const float* bt0 = (const float*)d_in[10];
    const float* g1  = (const float*)d_in[11];
    const float* bt1 = (const float*)d_in[12];
    const float* g2  = (const float*)d_in[13];
    const float* bt2 = (const float*)d_in[14];
    const float* wfc = (const float*)d_in[15];
    const float* bfc = (const float*)d_in[16];

    float* out   = (float*)d_out;                     // [NN,64]
    float* out_w = out + (size_t)NN*64;               // [NN,1]

    char* ws = (char*)d_ws;
    size_t off = 0;
    auto alloc = [&](size_t b){ size_t p = off; off += (b + 255) & ~(size_t)255; return ws + p; };

    unsigned* dego    = (unsigned*)alloc((size_t)NN*4);
    unsigned* degi    = (unsigned*)alloc((size_t)NN*4);
    float*    nsrc    = (float*)   alloc((size_t)NN*4);
    float*    ndst    = (float*)   alloc((size_t)NN*4);
    unsigned* offsets = (unsigned*)alloc((size_t)(NN+1)*4);    // node CSR offsets
    unsigned* cursor  = (unsigned*)alloc((size_t)NN*4);        // node fill cursors
    unsigned* bgc     = (unsigned*)alloc((size_t)NBG*4);       // (bucket,group) counts
    unsigned* bgoff   = (unsigned*)alloc((size_t)(NBG+1)*4);   // scanned offsets
    unsigned* bgcur   = (unsigned*)alloc((size_t)NBG*4);       // scatter cursors
    unsigned* bsumsA  = (unsigned*)alloc(512*4);
    unsigned* bsumsB  = (unsigned*)alloc(512*4);
    float*    stats   = (float*)   alloc(3*512*4);   // per layer: [sum|sumsq|scale|shift] x128
    int*      csr     = (int*)     alloc((size_t)NE*4);        // exact dst-sorted CSR
    float*    xn0     = (float*)   alloc((size_t)NN*32*4);     // h*nsrc padded
    float*    bufA    = (float*)   alloc((size_t)NN*128*4);    // GEMM out
    float*    bufB    = (float*)   alloc((size_t)NN*128*4);    // agg out (aliases pairs early)
    unsigned* bufC    = (unsigned*)alloc((size_t)NN*64*4);     // bf16 features
    (void)ws_size; (void)in_sizes; (void)n_in; (void)out_size;

    unsigned* pairs = (unsigned*)bufB;   // 6.4 MB, dead after k_fill2 (before bufB's first write)

    hipMemsetAsync(dego, 0, (size_t)NN*4, stream);
    hipMemsetAsync(degi, 0, (size_t)NN*4, stream);
    hipMemsetAsync(bgc,  0, (size_t)NBG*4, stream);
    hipMemsetAsync(stats, 0, 3*512*4, stream);

    const int NBn = (NN  + 511) / 512;   // 196 node-scan blocks
    const int NBb = (NBG + 511) / 512;   // 49 bucket-group-scan blocks

    k_hist<<<(NE + 255)/256, 256, 0, stream>>>(src, dst, dego, degi, bgc);
    k_node<<<(NN + 255)/256, 256, 0, stream>>>(h, dego, degi, nsrc, ndst, out_w, xn0);
    // node-level scan -> offsets, cursor
    k_scan1<<<NBn, 512, 0, stream>>>(degi, bsumsA, NN);
    k_scan2<<<1, 512, 0, stream>>>(bsumsA, offsets, NBn, NN, (unsigned)NE);
    k_scan3<<<NBn, 512, 0, stream>>>(degi, bsumsA, offsets, cursor, NN);
    // bucket-group scan -> bgoff, bgcur
    k_scan1<<<NBb, 512, 0, stream>>>(bgc, bsumsB, NBG);
    k_scan2<<<1, 512, 0, stream>>>(bsumsB, bgoff, NBb, NBG, (unsigned)NE);
    k_scan3<<<NBb, 512, 0, stream>>>(bgc, bsumsB, bgoff, bgcur, NBG);
    // two-pass CSR build
    k_bucket<<<(NE + CHUNK - 1)/CHUNK, 256, 0, stream>>>(src, dst, bgcur, pairs);
    k_fill2<<<NBK, 256, 0, stream>>>(bgoff, pairs, cursor, csr);

    // ---- layer 0: agg26 -> gemm 26x128 (+stats) -> bnfin -> apply->bf16 ----
    k_agg0<<<NN/2, 64, 0, stream>>>(xn0, offsets, csr, bufB);
    k_gemm<26,128,32,true><<<(NN + 63)/64, 256, 0, stream>>>(bufB, w0, b0, ndst, bufA, stats + 0*512);
    k_bnfin<<<1, 128, 0, stream>>>(stats + 0*512, g0, bt0);
    k_bnapply_bf<<<(NN*64 + 255)/256, 256, 0, stream>>>(bufA, stats + 0*512, nsrc, bufC);

    // ---- layer 1 ----
    k_agg_bf<<<NN, 64, 0, stream>>>(bufC, offsets, csr, bufB);
    k_gemm<128,128,128,true><<<(NN + 63)/64, 256, 0, stream>>>(bufB, w1, b1, ndst, bufA, stats + 1*512);
    k_bnfin<<<1, 128, 0, stream>>>(stats + 1*512, g1, bt1);
    k_bnapply_bf<<<(NN*64 + 255)/256, 256, 0, stream>>>(bufA, stats + 1*512, nsrc, bufC);

    // ---- layer 2 ----
    k_agg_bf<<<NN, 64, 0, stream>>>(bufC, offsets, csr, bufB);
    k_gemm<128,128,128,true><<<(NN + 63)/64, 256, 0, stream>>>(bufB, w2, b2, ndst, bufA, stats + 2*512);
    k_bnfin<<<1, 128, 0, stream>>>(stats + 2*512, g2, bt2);
    k_bnapply_f32<<<(NN*128 + 255)/256, 256, 0, stream>>>(bufA, stats + 2*512);

    // ---- FC: out = x @ wfc + bfc ----
    k_gemm<128,64,128,false><<<(NN + 63)/64, 256, 0, stream>>>(bufA, wfc, bfc, nullptr, out, nullptr);
}

// Round 5
// 760.882 us; speedup vs baseline: 4.1222x; 1.2369x over previous
//
#include <hip/hip_runtime.h>

#define NN 100000
#define NE 1600000
#define BN_EPS 1e-5f
#define BSHIFT 5
#define NBK (NN >> BSHIFT)          // 3125 buckets of exactly 32 nodes
#define NBG (NBK * 8)               // 25000 (bucket,group) cells
#define CHUNK 2048                  // edges per scatter block
#define CAPG 128                    // slots per (bucket,group) cell  (Poisson(64))
#define CAPB 1024                   // csr slots per bucket           (Poisson(512))

__constant__ float c_wtab[26] = {0.7f,0.9f,0.7f,0.9f,0.3f,0.7f,0.3f,0.9f,0.3f,0.3f,0.9f,0.7f,0.1f,
                                 0.9f,0.5f,0.9f,0.5f,0.5f,0.1f,0.3f,0.7f,0.9f,0.9f,0.9f,0.9f,0.9f};

__device__ __forceinline__ unsigned f2bf(float f){
    unsigned u = __float_as_uint(f);
    return (u + 0x7fffu + ((u >> 16) & 1u)) >> 16;   // round-to-nearest-even
}
__device__ __forceinline__ float bflo(unsigned v){ return __uint_as_float(v << 16); }
__device__ __forceinline__ float bfhi(unsigned v){ return __uint_as_float(v & 0xffff0000u); }

// ---------------- single pass: dego histogram + fixed-capacity bucket scatter ----------------
__global__ __launch_bounds__(256) void k_bucket(const int* __restrict__ src,
                                                const int* __restrict__ dst,
                                                unsigned* __restrict__ dego,
                                                unsigned* __restrict__ bgcnt,
                                                unsigned* __restrict__ pairs){
    int base = blockIdx.x*CHUNK;
    unsigned g = (unsigned)(blockIdx.x & 7);
    #pragma unroll
    for (int k = 0; k < CHUNK/256; ++k){
        int e = base + k*256 + threadIdx.x;
        if (e < NE){
            int d = dst[e], s = src[e];
            atomicAdd(&dego[s], 1u);
            unsigned cell = (unsigned)(d >> BSHIFT)*8u + g;
            unsigned p = atomicAdd(&bgcnt[cell], 1u);
            if (p < CAPG)
                pairs[(size_t)cell*CAPG + p] = ((unsigned)(d & 31) << 17) | (unsigned)s;
        }
    }
}

// ---------------- block-per-bucket: LDS count + scan + place (no global atomics) ----------------
__global__ __launch_bounds__(256) void k_fill3(const unsigned* __restrict__ bgcnt,
                                               const unsigned* __restrict__ pairs,
                                               int* __restrict__ csr,
                                               unsigned* __restrict__ offs,
                                               unsigned* __restrict__ degi){
    __shared__ unsigned cnt[32], cur[32], gn[8];
    int b = blockIdx.x, tid = threadIdx.x;
    if (tid < 32) cnt[tid] = 0;
    if (tid < 8){
        unsigned n = bgcnt[b*8 + tid];
        gn[tid] = n > CAPG ? CAPG : n;
    }
    __syncthreads();
    int w = tid >> 6, lane = tid & 63;
    // pass 1: per-node counts (each wave handles groups w and w+4)
    #pragma unroll
    for (int gg = 0; gg < 2; ++gg){
        int g = w + gg*4;
        unsigned n = gn[g];
        const unsigned* P = pairs + (size_t)(b*8 + g)*CAPG;
        for (unsigned i = lane; i < n; i += 64)
            atomicAdd(&cnt[P[i] >> 17], 1u);
    }
    __syncthreads();
    if (tid == 0){
        unsigned run = 0;
        #pragma unroll
        for (int i = 0; i < 32; ++i){ cur[i] = run; run += cnt[i]; }
    }
    __syncthreads();
    if (tid < 32){
        offs[(b << BSHIFT) + tid] = (unsigned)(b*CAPB) + cur[tid];
        degi[(b << BSHIFT) + tid] = cnt[tid];
    }
    __syncthreads();
    // pass 2: place into csr (LDS cursors, block-private 4KB region)
    #pragma unroll
    for (int gg = 0; gg < 2; ++gg){
        int g = w + gg*4;
        unsigned n = gn[g];
        const unsigned* P = pairs + (size_t)(b*8 + g)*CAPG;
        for (unsigned i = lane; i < n; i += 64){
            unsigned pr = P[i];
            unsigned p = atomicAdd(&cur[pr >> 17], 1u);
            csr[(size_t)b*CAPB + p] = (int)(pr & 0x1FFFFu);
        }
    }
}

// ---------------- per-node: norms + argmax weight + xn0 = h*nsrc (padded [N,32]) ----------------
__global__ void k_node(const float* __restrict__ h, const unsigned* __restrict__ dego,
                       const unsigned* __restrict__ degi, float* __restrict__ nsrc,
                       float* __restrict__ ndst, float* __restrict__ outw,
                       float* __restrict__ xn0){
    int i = blockIdx.x*blockDim.x + threadIdx.x;
    if (i < NN){
        float d0 = (float)dego[i]; d0 = d0 < 1.f ? 1.f : d0;
        float d1 = (float)degi[i]; d1 = d1 < 1.f ? 1.f : d1;
        float ns = rsqrtf(d0);
        nsrc[i] = ns;
        ndst[i] = rsqrtf(d1);
        float row[26];
        #pragma unroll
        for (int c = 0; c < 26; ++c) row[c] = h[(size_t)i*26 + c];
        float best = row[0]; int bi = 0;
        #pragma unroll
        for (int c = 1; c < 26; ++c){ if (row[c] > best){ best = row[c]; bi = c; } }
        outw[i] = c_wtab[bi];
        #pragma unroll
        for (int c = 0; c < 26; ++c) xn0[(size_t)i*32 + c] = row[c]*ns;
        #pragma unroll
        for (int c = 26; c < 32; ++c) xn0[(size_t)i*32 + c] = 0.f;
    }
}

// ---------------- layer-0 aggregation: fp32 [N,32]-padded, 2 nodes per wave ----------------
__global__ __launch_bounds__(64) void k_agg0(const float* __restrict__ xn,
                                             const unsigned* __restrict__ offs,
                                             const unsigned* __restrict__ degi,
                                             const int* __restrict__ csr,
                                             float* __restrict__ agg){
    int node = blockIdx.x*2 + (threadIdx.x >> 5);
    int c = threadIdx.x & 31;
    unsigned beg = offs[node], end = beg + degi[node];
    float acc = 0.f;
    unsigned e = beg;
    for (; e + 4 <= end; e += 4){
        int s0 = csr[e+0], s1 = csr[e+1], s2 = csr[e+2], s3 = csr[e+3];
        float a0 = xn[(size_t)s0*32 + c];
        float a1 = xn[(size_t)s1*32 + c];
        float a2 = xn[(size_t)s2*32 + c];
        float a3 = xn[(size_t)s3*32 + c];
        acc += (a0 + a1) + (a2 + a3);
    }
    for (; e < end; ++e)
        acc += xn[(size_t)csr[e]*32 + c];
    agg[(size_t)node*32 + c] = acc;
}

// ---------------- layers 1/2 aggregation: bf16 gather, register accumulate, 8-unroll ----------------
__global__ __launch_bounds__(64) void k_agg_bf(const unsigned* __restrict__ xn,
                                               const unsigned* __restrict__ offs,
                                               const unsigned* __restrict__ degi,
                                               const int* __restrict__ csr,
                                               float* __restrict__ agg){
    int node = blockIdx.x;
    int t = threadIdx.x;   // dword t = channels (2t, 2t+1)
    unsigned beg = offs[node], end = beg + degi[node];
    float a0 = 0.f, a1 = 0.f;
    unsigned e = beg;
    for (; e + 8 <= end; e += 8){
        int s[8];
        #pragma unroll
        for (int i = 0; i < 8; ++i) s[i] = csr[e + i];
        #pragma unroll
        for (int i = 0; i < 8; ++i){
            unsigned v = xn[(size_t)s[i]*64 + t];
            a0 += bflo(v);
            a1 += bfhi(v);
        }
    }
    for (; e < end; ++e){
        unsigned v = xn[(size_t)csr[e]*64 + t];
        a0 += bflo(v);
        a1 += bfhi(v);
    }
    reinterpret_cast<float2*>(agg + (size_t)node*128)[t] = make_float2(a0, a1);
}

// ---------------- GEMM: Z = A @ W (*ndst) + bias, optional fused BN stats ----------------
template<int CIN, int COUT, int LDA, bool STATS>
__global__ __launch_bounds__(256) void k_gemm(const float* __restrict__ A,
                                              const float* __restrict__ W,
                                              const float* __restrict__ bias,
                                              const float* __restrict__ ndst,
                                              float* __restrict__ Z,
                                              float* __restrict__ stats){
    constexpr int ROWS = 64;
    constexpr int KC = 32;
    constexpr int CG = COUT / 8;          // col groups of 8
    constexpr int TPB = 256;
    constexpr int RPT = ROWS * CG / TPB;  // rows per thread
    __shared__ float sW[KC][COUT];
    __shared__ float sA[ROWS][KC + 1];
    __shared__ float sS[2][COUT];
    const int tid = threadIdx.x;
    const int cg  = tid % CG;
    const int rg  = tid / CG;
    const int row0 = blockIdx.x * ROWS;
    float acc[RPT][8];
    #pragma unroll
    for (int r = 0; r < RPT; ++r)
        #pragma unroll
        for (int c = 0; c < 8; ++c) acc[r][c] = 0.f;

    for (int k0 = 0; k0 < CIN; k0 += KC){
        const int kc = (CIN - k0) < KC ? (CIN - k0) : KC;
        for (int idx = tid; idx < kc*COUT; idx += TPB){
            int kk = idx / COUT, c = idx - kk*COUT;
            sW[kk][c] = W[(k0 + kk)*COUT + c];
        }
        for (int idx = tid; idx < ROWS*kc; idx += TPB){
            int r = idx / kc, kk = idx - r*kc;
            int gr = row0 + r;
            sA[r][kk] = (gr < NN) ? A[(size_t)gr*LDA + k0 + kk] : 0.f;
        }
        __syncthreads();
        for (int kk = 0; kk < kc; ++kk){
            float w[8];
            #pragma unroll
            for (int c = 0; c < 8; ++c) w[c] = sW[kk][cg*8 + c];
            #pragma unroll
            for (int r = 0; r < RPT; ++r){
                float a = sA[rg*RPT + r][kk];
                #pragma unroll
                for (int c = 0; c < 8; ++c) acc[r][c] += a * w[c];
            }
        }
        __syncthreads();
    }
    if (STATS){
        for (int i = tid; i < 2*COUT; i += TPB) (&sS[0][0])[i] = 0.f;
    }
    __syncthreads();
    float cs[8], cq[8];
    #pragma unroll
    for (int c = 0; c < 8; ++c){ cs[c] = 0.f; cq[c] = 0.f; }
    #pragma unroll
    for (int r = 0; r < RPT; ++r){
        int gr = row0 + rg*RPT + r;
        if (gr < NN){
            float nm = ndst ? ndst[gr] : 1.f;
            float z[8];
            #pragma unroll
            for (int c = 0; c < 8; ++c){
                z[c] = acc[r][c]*nm + bias[cg*8 + c];
                if (STATS){ cs[c] += z[c]; cq[c] += z[c]*z[c]; }
            }
            float* zp = &Z[(size_t)gr*COUT + cg*8];
            reinterpret_cast<float4*>(zp)[0] = make_float4(z[0], z[1], z[2], z[3]);
            reinterpret_cast<float4*>(zp)[1] = make_float4(z[4], z[5], z[6], z[7]);
        }
    }
    if (STATS){
        #pragma unroll
        for (int c = 0; c < 8; ++c){
            atomicAdd(&sS[0][cg*8 + c], cs[c]);
            atomicAdd(&sS[1][cg*8 + c], cq[c]);
        }
        __syncthreads();
        for (int i = tid; i < COUT; i += TPB){
            atomicAdd(&stats[i],        sS[0][i]);
            atomicAdd(&stats[128 + i],  sS[1][i]);
        }
    }
}

// ---------------- BN finalize: scale/shift ----------------
__global__ void k_bnfin(float* __restrict__ stats, const float* __restrict__ g,
                        const float* __restrict__ bt){
    int c = threadIdx.x;  // 128
    float mu  = stats[c] / (float)NN;
    float var = stats[128 + c] / (float)NN - mu*mu;
    if (var < 0.f) var = 0.f;
    float sc = g[c] * rsqrtf(var + BN_EPS);
    stats[256 + c] = sc;
    stats[384 + c] = bt[c] - mu*sc;
}

// ---------------- BN apply + ReLU + *nsrc -> bf16, dword d = (ch 2d, ch 2d+1) ----------------
__global__ void k_bnapply_bf(const float* __restrict__ X, const float* __restrict__ stats,
                             const float* __restrict__ nsrc, unsigned* __restrict__ out){
    int idx = blockIdx.x*blockDim.x + threadIdx.x;
    if (idx < NN*64){
        int d = idx & 63;
        int node = idx >> 6;
        int c0 = d << 1;
        float2 x = reinterpret_cast<const float2*>(X)[idx];
        float ns = nsrc[node];
        float v0 = x.x*stats[256 + c0]     + stats[384 + c0];
        float v1 = x.y*stats[256 + c0 + 1] + stats[384 + c0 + 1];
        v0 = v0 > 0.f ? v0*ns : 0.f;
        v1 = v1 > 0.f ? v1*ns : 0.f;
        out[idx] = f2bf(v0) | (f2bf(v1) << 16);
    }
}

// ---------------- BN apply + ReLU, fp32 in place (layer 2) ----------------
__global__ void k_bnapply_f32(float* __restrict__ X, const float* __restrict__ stats){
    int idx = blockIdx.x*blockDim.x + threadIdx.x;
    const int total = NN * 128;
    if (idx < total){
        int c = idx & 127;
        float v = X[idx]*stats[256 + c] + stats[384 + c];
        X[idx] = v > 0.f ? v : 0.f;
    }
}

extern "C" void kernel_launch(void* const* d_in, const int* in_sizes, int n_in,
                              void* d_out, int out_size, void* d_ws, size_t ws_size,
                              hipStream_t stream) {
    const float* h   = (const float*)d_in[0];
    const int*   src = (const int*)d_in[1];
    const int*   dst = (const int*)d_in[2];
    const float* w0  = (const float*)d_in[3];
    const float* b0  = (const float*)d_in[4];
    const float* w1  = (const float*)d_in[5];
    const float* b1  = (const float*)d_in[6];
    const float* w2  = (const float*)d_in[7];
    const float* b2  = (const float*)d_in[8];
    const float* g0  = (const float*)d_in[9];
    const float* bt0 = (const float*)d_in[10];
    const float* g1  = (const float*)d_in[11];
    const float* bt1 = (const float*)d_in[12];
    const float* g2  = (const float*)d_in[13];
    const float* bt2 = (const float*)d_in[14];
    const float* wfc = (const float*)d_in[15];
    const float* bfc = (const float*)d_in[16];

    float* out   = (float*)d_out;                     // [NN,64]
    float* out_w = out + (size_t)NN*64;               // [NN,1]

    char* ws = (char*)d_ws;
    size_t off = 0;
    auto alloc = [&](size_t b){ size_t p = off; off += (b + 255) & ~(size_t)255; return ws + p; };

    unsigned* dego    = (unsigned*)alloc((size_t)NN*4);
    unsigned* degi    = (unsigned*)alloc((size_t)NN*4);
    float*    nsrc    = (float*)   alloc((size_t)NN*4);
    float*    ndst    = (float*)   alloc((size_t)NN*4);
    unsigned* offsets = (unsigned*)alloc((size_t)NN*4);        // node -> csr base
    unsigned* bgcnt   = (unsigned*)alloc((size_t)NBG*4);       // (bucket,group) cell counts
    float*    stats   = (float*)   alloc(3*512*4);   // per layer: [sum|sumsq|scale|shift] x128
    int*      csr     = (int*)     alloc((size_t)NBK*CAPB*4);  // 12.8 MB fixed-capacity CSR
    float*    xn0     = (float*)   alloc((size_t)NN*32*4);     // h*nsrc padded
    float*    bufA    = (float*)   alloc((size_t)NN*128*4);    // GEMM out
    float*    bufB    = (float*)   alloc((size_t)NN*128*4);    // agg out (aliases pairs early)
    unsigned* bufC    = (unsigned*)alloc((size_t)NN*64*4);     // bf16 features
    (void)ws_size; (void)in_sizes; (void)n_in; (void)out_size;

    unsigned* pairs = (unsigned*)bufB;   // 12.8 MB, dead after k_fill3 (before bufB's first write)

    hipMemsetAsync(dego, 0, (size_t)NN*4, stream);
    hipMemsetAsync(bgcnt, 0, (size_t)NBG*4, stream);
    hipMemsetAsync(stats, 0, 3*512*4, stream);

    // ---- build: bucket scatter -> per-bucket CSR (+degi) -> node params ----
    k_bucket<<<(NE + CHUNK - 1)/CHUNK, 256, 0, stream>>>(src, dst, dego, bgcnt, pairs);
    k_fill3<<<NBK, 256, 0, stream>>>(bgcnt, pairs, csr, offsets, degi);
    k_node<<<(NN + 255)/256, 256, 0, stream>>>(h, dego, degi, nsrc, ndst, out_w, xn0);

    // ---- layer 0: agg26 -> gemm 26x128 (+stats) -> bnfin -> apply->bf16 ----
    k_agg0<<<NN/2, 64, 0, stream>>>(xn0, offsets, degi, csr, bufB);
    k_gemm<26,128,32,true><<<(NN + 63)/64, 256, 0, stream>>>(bufB, w0, b0, ndst, bufA, stats + 0*512);
    k_bnfin<<<1, 128, 0, stream>>>(stats + 0*512, g0, bt0);
    k_bnapply_bf<<<(NN*64 + 255)/256, 256, 0, stream>>>(bufA, stats + 0*512, nsrc, bufC);

    // ---- layer 1 ----
    k_agg_bf<<<NN, 64, 0, stream>>>(bufC, offsets, degi, csr, bufB);
    k_gemm<128,128,128,true><<<(NN + 63)/64, 256, 0, stream>>>(bufB, w1, b1, ndst, bufA, stats + 1*512);
    k_bnfin<<<1, 128, 0, stream>>>(stats + 1*512, g1, bt1);
    k_bnapply_bf<<<(NN*64 + 255)/256, 256, 0, stream>>>(bufA, stats + 1*512, nsrc, bufC);

    // ---- layer 2 ----
    k_agg_bf<<<NN, 64, 0, stream>>>(bufC, offsets, degi, csr, bufB);
    k_gemm<128,128,128,true><<<(NN + 63)/64, 256, 0, stream>>>(bufB, w2, b2, ndst, bufA, stats + 2*512);
    k_bnfin<<<1, 128, 0, stream>>>(stats + 2*512, g2, bt2);
    k_bnapply_f32<<<(NN*128 + 255)/256, 256, 0, stream>>>(bufA, stats + 2*512);

    // ---- FC: out = x @ wfc + bfc ----
    k_gemm<128,64,128,false><<<(NN + 63)/64, 256, 0, stream>>>(bufA, wfc, bfc, nullptr, out, nullptr);
}

// Round 6
// 673.594 us; speedup vs baseline: 4.6563x; 1.1296x over previous
//
#include <hip/hip_runtime.h>

#define NN 100000
#define NE 1600000
#define BN_EPS 1e-5f
#define BSHIFT 5
#define NBK (NN >> BSHIFT)          // 3125 buckets of exactly 32 nodes
#define NBG (NBK * 8)               // 25000 (bucket,group) cells
#define EPB 16384                   // edges per bucket-block
#define NBLK ((NE + EPB - 1)/EPB)   // 98 scatter blocks
#define CAPG 128                    // slots per (bucket,group) cell  (mean 64, +8 sigma)
#define CAPB 1024                   // csr slots per bucket = 8*CAPG (exact bound)

__constant__ float c_wtab[26] = {0.7f,0.9f,0.7f,0.9f,0.3f,0.7f,0.3f,0.9f,0.3f,0.3f,0.9f,0.7f,0.1f,
                                 0.9f,0.5f,0.9f,0.5f,0.5f,0.1f,0.3f,0.7f,0.9f,0.9f,0.9f,0.9f,0.9f};

__device__ __forceinline__ unsigned f2bf(float f){
    unsigned u = __float_as_uint(f);
    return (u + 0x7fffu + ((u >> 16) & 1u)) >> 16;   // round-to-nearest-even
}
__device__ __forceinline__ float bflo(unsigned v){ return __uint_as_float(v << 16); }
__device__ __forceinline__ float bfhi(unsigned v){ return __uint_as_float(v & 0xffff0000u); }

// ---- bucket scatter with LDS-amortized reservations (dst pairs + src tokens) ----
__global__ __launch_bounds__(512) void k_bucket2(const int* __restrict__ src,
                                                 const int* __restrict__ dst,
                                                 unsigned* __restrict__ gcD,
                                                 unsigned* __restrict__ gcS,
                                                 unsigned* __restrict__ pairsD,
                                                 unsigned* __restrict__ tokS){
    __shared__ unsigned lcD[NBK], lcS[NBK];
    int tid = threadIdx.x;
    for (int i = tid; i < NBK; i += 512){ lcD[i] = 0u; lcS[i] = 0u; }
    __syncthreads();
    int base = blockIdx.x*EPB;
    unsigned g = (unsigned)(blockIdx.x & 7);
    int nEdge = NE - base; if (nEdge > EPB) nEdge = EPB;
    // phase A: LDS histograms over 3125 buckets (dst and src)
    for (int k = tid; k < nEdge; k += 512){
        int e = base + k;
        atomicAdd(&lcD[(unsigned)dst[e] >> BSHIFT], 1u);
        atomicAdd(&lcS[(unsigned)src[e] >> BSHIFT], 1u);
    }
    __syncthreads();
    // phase B: one global reservation per touched cell; lc* becomes cursor base
    for (int i = tid; i < NBK; i += 512){
        unsigned c = lcD[i];
        lcD[i] = c ? atomicAdd(&gcD[(unsigned)i*8u + g], c) : 0u;
        c = lcS[i];
        lcS[i] = c ? atomicAdd(&gcS[(unsigned)i*8u + g], c) : 0u;
    }
    __syncthreads();
    // phase C: place edges via LDS cursors
    for (int k = tid; k < nEdge; k += 512){
        int e = base + k;
        int d = dst[e], s = src[e];
        unsigned pd = atomicAdd(&lcD[(unsigned)d >> BSHIFT], 1u);
        if (pd < CAPG)
            pairsD[((size_t)((unsigned)d >> BSHIFT)*8u + g)*CAPG + pd] =
                ((unsigned)(d & 31) << 17) | (unsigned)s;
        unsigned ps = atomicAdd(&lcS[(unsigned)s >> BSHIFT], 1u);
        if (ps < CAPG)
            tokS[((size_t)((unsigned)s >> BSHIFT)*8u + g)*CAPG + ps] = (unsigned)(s & 31);
    }
}

// ---- block-per-bucket: CSR build + degi + dego, zero global atomics ----
__global__ __launch_bounds__(256) void k_fill4(const unsigned* __restrict__ gcD,
                                               const unsigned* __restrict__ gcS,
                                               const unsigned* __restrict__ pairsD,
                                               const unsigned* __restrict__ tokS,
                                               int* __restrict__ csr,
                                               unsigned* __restrict__ offs,
                                               unsigned* __restrict__ degi,
                                               unsigned* __restrict__ dego){
    __shared__ unsigned cnt[32], cur[32], scnt[32], gnD[8], gnS[8];
    int b = blockIdx.x, tid = threadIdx.x;
    if (tid < 32){ cnt[tid] = 0u; scnt[tid] = 0u; }
    if (tid < 8){
        unsigned n = gcD[b*8 + tid]; gnD[tid] = n > CAPG ? CAPG : n;
        n = gcS[b*8 + tid];          gnS[tid] = n > CAPG ? CAPG : n;
    }
    __syncthreads();
    int w = tid >> 6, lane = tid & 63;
    #pragma unroll
    for (int gg = 0; gg < 2; ++gg){
        int g = w + gg*4;
        {
            unsigned n = gnD[g];
            const unsigned* P = pairsD + ((size_t)b*8 + g)*CAPG;
            for (unsigned i = lane; i < n; i += 64)
                atomicAdd(&cnt[P[i] >> 17], 1u);
        }
        {
            unsigned n = gnS[g];
            const unsigned* T = tokS + ((size_t)b*8 + g)*CAPG;
            for (unsigned i = lane; i < n; i += 64)
                atomicAdd(&scnt[T[i] & 31], 1u);
        }
    }
    __syncthreads();
    if (tid == 0){
        unsigned run = 0;
        #pragma unroll
        for (int i = 0; i < 32; ++i){ cur[i] = run; run += cnt[i]; }
    }
    __syncthreads();
    if (tid < 32){
        offs[(b << BSHIFT) + tid] = (unsigned)(b*CAPB) + cur[tid];
        degi[(b << BSHIFT) + tid] = cnt[tid];
        dego[(b << BSHIFT) + tid] = scnt[tid];
    }
    __syncthreads();
    #pragma unroll
    for (int gg = 0; gg < 2; ++gg){
        int g = w + gg*4;
        unsigned n = gnD[g];
        const unsigned* P = pairsD + ((size_t)b*8 + g)*CAPG;
        for (unsigned i = lane; i < n; i += 64){
            unsigned pr = P[i];
            unsigned p = atomicAdd(&cur[pr >> 17], 1u);
            csr[(size_t)b*CAPB + p] = (int)(pr & 0x1FFFFu);
        }
    }
}

// ---------------- per-node: norms + argmax weight + xn0 = h*nsrc (padded [N,32]) ----------------
__global__ void k_node(const float* __restrict__ h, const unsigned* __restrict__ dego,
                       const unsigned* __restrict__ degi, float* __restrict__ nsrc,
                       float* __restrict__ ndst, float* __restrict__ outw,
                       float* __restrict__ xn0){
    int i = blockIdx.x*blockDim.x + threadIdx.x;
    if (i < NN){
        float d0 = (float)dego[i]; d0 = d0 < 1.f ? 1.f : d0;
        float d1 = (float)degi[i]; d1 = d1 < 1.f ? 1.f : d1;
        float ns = rsqrtf(d0);
        nsrc[i] = ns;
        ndst[i] = rsqrtf(d1);
        float row[26];
        #pragma unroll
        for (int c = 0; c < 26; ++c) row[c] = h[(size_t)i*26 + c];
        float best = row[0]; int bi = 0;
        #pragma unroll
        for (int c = 1; c < 26; ++c){ if (row[c] > best){ best = row[c]; bi = c; } }
        outw[i] = c_wtab[bi];
        #pragma unroll
        for (int c = 0; c < 26; ++c) xn0[(size_t)i*32 + c] = row[c]*ns;
        #pragma unroll
        for (int c = 26; c < 32; ++c) xn0[(size_t)i*32 + c] = 0.f;
    }
}

// ---------------- layer-0 aggregation: fp32 [N,32]-padded, 2 nodes per wave ----------------
__global__ __launch_bounds__(64) void k_agg0(const float* __restrict__ xn,
                                             const unsigned* __restrict__ offs,
                                             const unsigned* __restrict__ degi,
                                             const int* __restrict__ csr,
                                             float* __restrict__ agg){
    int node = blockIdx.x*2 + (threadIdx.x >> 5);
    int c = threadIdx.x & 31;
    unsigned beg = offs[node], end = beg + degi[node];
    float acc = 0.f;
    unsigned e = beg;
    for (; e + 4 <= end; e += 4){
        int s0 = csr[e+0], s1 = csr[e+1], s2 = csr[e+2], s3 = csr[e+3];
        float a0 = xn[(size_t)s0*32 + c];
        float a1 = xn[(size_t)s1*32 + c];
        float a2 = xn[(size_t)s2*32 + c];
        float a3 = xn[(size_t)s3*32 + c];
        acc += (a0 + a1) + (a2 + a3);
    }
    for (; e < end; ++e)
        acc += xn[(size_t)csr[e]*32 + c];
    agg[(size_t)node*32 + c] = acc;
}

// ---------------- layers 1/2 aggregation: bf16 gather, register accumulate, 8-unroll ----------------
__global__ __launch_bounds__(64) void k_agg_bf(const unsigned* __restrict__ xn,
                                               const unsigned* __restrict__ offs,
                                               const unsigned* __restrict__ degi,
                                               const int* __restrict__ csr,
                                               float* __restrict__ agg){
    int node = blockIdx.x;
    int t = threadIdx.x;   // dword t = channels (2t, 2t+1)
    unsigned beg = offs[node], end = beg + degi[node];
    float a0 = 0.f, a1 = 0.f;
    unsigned e = beg;
    for (; e + 8 <= end; e += 8){
        int s[8];
        #pragma unroll
        for (int i = 0; i < 8; ++i) s[i] = csr[e + i];
        #pragma unroll
        for (int i = 0; i < 8; ++i){
            unsigned v = xn[(size_t)s[i]*64 + t];
            a0 += bflo(v);
            a1 += bfhi(v);
        }
    }
    for (; e < end; ++e){
        unsigned v = xn[(size_t)csr[e]*64 + t];
        a0 += bflo(v);
        a1 += bfhi(v);
    }
    reinterpret_cast<float2*>(agg + (size_t)node*128)[t] = make_float2(a0, a1);
}

// ---------------- GEMM: Z = A @ W (*ndst) + bias, optional fused BN stats ----------------
template<int CIN, int COUT, int LDA, bool STATS>
__global__ __launch_bounds__(256) void k_gemm(const float* __restrict__ A,
                                              const float* __restrict__ W,
                                              const float* __restrict__ bias,
                                              const float* __restrict__ ndst,
                                              float* __restrict__ Z,
                                              float* __restrict__ stats){
    constexpr int ROWS = 64;
    constexpr int KC = 32;
    constexpr int CG = COUT / 8;          // col groups of 8
    constexpr int TPB = 256;
    constexpr int RPT = ROWS * CG / TPB;  // rows per thread
    __shared__ float sW[KC][COUT];
    __shared__ float sA[ROWS][KC + 1];
    __shared__ float sS[2][COUT];
    const int tid = threadIdx.x;
    const int cg  = tid % CG;
    const int rg  = tid / CG;
    const int row0 = blockIdx.x * ROWS;
    float acc[RPT][8];
    #pragma unroll
    for (int r = 0; r < RPT; ++r)
        #pragma unroll
        for (int c = 0; c < 8; ++c) acc[r][c] = 0.f;

    for (int k0 = 0; k0 < CIN; k0 += KC){
        const int kc = (CIN - k0) < KC ? (CIN - k0) : KC;
        for (int idx = tid; idx < kc*COUT; idx += TPB){
            int kk = idx / COUT, c = idx - kk*COUT;
            sW[kk][c] = W[(k0 + kk)*COUT + c];
        }
        for (int idx = tid; idx < ROWS*kc; idx += TPB){
            int r = idx / kc, kk = idx - r*kc;
            int gr = row0 + r;
            sA[r][kk] = (gr < NN) ? A[(size_t)gr*LDA + k0 + kk] : 0.f;
        }
        __syncthreads();
        for (int kk = 0; kk < kc; ++kk){
            float w[8];
            #pragma unroll
            for (int c = 0; c < 8; ++c) w[c] = sW[kk][cg*8 + c];
            #pragma unroll
            for (int r = 0; r < RPT; ++r){
                float a = sA[rg*RPT + r][kk];
                #pragma unroll
                for (int c = 0; c < 8; ++c) acc[r][c] += a * w[c];
            }
        }
        __syncthreads();
    }
    if (STATS){
        for (int i = tid; i < 2*COUT; i += TPB) (&sS[0][0])[i] = 0.f;
    }
    __syncthreads();
    float cs[8], cq[8];
    #pragma unroll
    for (int c = 0; c < 8; ++c){ cs[c] = 0.f; cq[c] = 0.f; }
    #pragma unroll
    for (int r = 0; r < RPT; ++r){
        int gr = row0 + rg*RPT + r;
        if (gr < NN){
            float nm = ndst ? ndst[gr] : 1.f;
            float z[8];
            #pragma unroll
            for (int c = 0; c < 8; ++c){
                z[c] = acc[r][c]*nm + bias[cg*8 + c];
                if (STATS){ cs[c] += z[c]; cq[c] += z[c]*z[c]; }
            }
            float* zp = &Z[(size_t)gr*COUT + cg*8];
            reinterpret_cast<float4*>(zp)[0] = make_float4(z[0], z[1], z[2], z[3]);
            reinterpret_cast<float4*>(zp)[1] = make_float4(z[4], z[5], z[6], z[7]);
        }
    }
    if (STATS){
        #pragma unroll
        for (int c = 0; c < 8; ++c){
            atomicAdd(&sS[0][cg*8 + c], cs[c]);
            atomicAdd(&sS[1][cg*8 + c], cq[c]);
        }
        __syncthreads();
        for (int i = tid; i < COUT; i += TPB){
            atomicAdd(&stats[i],        sS[0][i]);
            atomicAdd(&stats[128 + i],  sS[1][i]);
        }
    }
}

// ---------------- BN finalize: scale/shift ----------------
__global__ void k_bnfin(float* __restrict__ stats, const float* __restrict__ g,
                        const float* __restrict__ bt){
    int c = threadIdx.x;  // 128
    float mu  = stats[c] / (float)NN;
    float var = stats[128 + c] / (float)NN - mu*mu;
    if (var < 0.f) var = 0.f;
    float sc = g[c] * rsqrtf(var + BN_EPS);
    stats[256 + c] = sc;
    stats[384 + c] = bt[c] - mu*sc;
}

// ---------------- BN apply + ReLU + *nsrc -> bf16, dword d = (ch 2d, ch 2d+1) ----------------
__global__ void k_bnapply_bf(const float* __restrict__ X, const float* __restrict__ stats,
                             const float* __restrict__ nsrc, unsigned* __restrict__ out){
    int idx = blockIdx.x*blockDim.x + threadIdx.x;
    if (idx < NN*64){
        int d = idx & 63;
        int node = idx >> 6;
        int c0 = d << 1;
        float2 x = reinterpret_cast<const float2*>(X)[idx];
        float ns = nsrc[node];
        float v0 = x.x*stats[256 + c0]     + stats[384 + c0];
        float v1 = x.y*stats[256 + c0 + 1] + stats[384 + c0 + 1];
        v0 = v0 > 0.f ? v0*ns : 0.f;
        v1 = v1 > 0.f ? v1*ns : 0.f;
        out[idx] = f2bf(v0) | (f2bf(v1) << 16);
    }
}

// ---------------- BN apply + ReLU, fp32 in place (layer 2) ----------------
__global__ void k_bnapply_f32(float* __restrict__ X, const float* __restrict__ stats){
    int idx = blockIdx.x*blockDim.x + threadIdx.x;
    const int total = NN * 128;
    if (idx < total){
        int c = idx & 127;
        float v = X[idx]*stats[256 + c] + stats[384 + c];
        X[idx] = v > 0.f ? v : 0.f;
    }
}

extern "C" void kernel_launch(void* const* d_in, const int* in_sizes, int n_in,
                              void* d_out, int out_size, void* d_ws, size_t ws_size,
                              hipStream_t stream) {
    const float* h   = (const float*)d_in[0];
    const int*   src = (const int*)d_in[1];
    const int*   dst = (const int*)d_in[2];
    const float* w0  = (const float*)d_in[3];
    const float* b0  = (const float*)d_in[4];
    const float* w1  = (const float*)d_in[5];
    const float* b1  = (const float*)d_in[6];
    const float* w2  = (const float*)d_in[7];
    const float* b2  = (const float*)d_in[8];
    const float* g0  = (const float*)d_in[9];
    const float* bt0 = (const float*)d_in[10];
    const float* g1  = (const float*)d_in[11];
    const float* bt1 = (const float*)d_in[12];
    const float* g2  = (const float*)d_in[13];
    const float* bt2 = (const float*)d_in[14];
    const float* wfc = (const float*)d_in[15];
    const float* bfc = (const float*)d_in[16];

    float* out   = (float*)d_out;                     // [NN,64]
    float* out_w = out + (size_t)NN*64;               // [NN,1]

    char* ws = (char*)d_ws;
    size_t off = 0;
    auto alloc = [&](size_t b){ size_t p = off; off += (b + 255) & ~(size_t)255; return ws + p; };

    unsigned* dego    = (unsigned*)alloc((size_t)NN*4);
    unsigned* degi    = (unsigned*)alloc((size_t)NN*4);
    float*    nsrc    = (float*)   alloc((size_t)NN*4);
    float*    ndst    = (float*)   alloc((size_t)NN*4);
    unsigned* offsets = (unsigned*)alloc((size_t)NN*4);        // node -> csr base
    unsigned* gcD     = (unsigned*)alloc((size_t)NBG*4);       // dst (bucket,g) cell counts
    unsigned* gcS     = (unsigned*)alloc((size_t)NBG*4);       // src (bucket,g) cell counts
    float*    stats   = (float*)   alloc(3*512*4);   // per layer: [sum|sumsq|scale|shift] x128
    int*      csr     = (int*)     alloc((size_t)NBK*CAPB*4);  // 12.8 MB fixed-capacity CSR
    float*    xn0     = (float*)   alloc((size_t)NN*32*4);     // h*nsrc padded
    float*    bufA    = (float*)   alloc((size_t)NN*128*4);    // GEMM out
    float*    bufB    = (float*)   alloc((size_t)NN*128*4);    // agg out (aliases pairs early)
    unsigned* bufC    = (unsigned*)alloc((size_t)NN*64*4);     // bf16 features
    (void)ws_size; (void)in_sizes; (void)n_in; (void)out_size;

    unsigned* pairsD = (unsigned*)bufB;                        // 12.8 MB
    unsigned* tokS   = (unsigned*)bufB + (size_t)NBG*CAPG;     // 12.8 MB, both dead after k_fill4

    hipMemsetAsync(gcD, 0, (size_t)NBG*4, stream);
    hipMemsetAsync(gcS, 0, (size_t)NBG*4, stream);
    hipMemsetAsync(stats, 0, 3*512*4, stream);

    // ---- build: LDS-amortized bucket scatter -> per-bucket CSR + degrees -> node params ----
    k_bucket2<<<NBLK, 512, 0, stream>>>(src, dst, gcD, gcS, pairsD, tokS);
    k_fill4<<<NBK, 256, 0, stream>>>(gcD, gcS, pairsD, tokS, csr, offsets, degi, dego);
    k_node<<<(NN + 255)/256, 256, 0, stream>>>(h, dego, degi, nsrc, ndst, out_w, xn0);

    // ---- layer 0: agg26 -> gemm 26x128 (+stats) -> bnfin -> apply->bf16 ----
    k_agg0<<<NN/2, 64, 0, stream>>>(xn0, offsets, degi, csr, bufB);
    k_gemm<26,128,32,true><<<(NN + 63)/64, 256, 0, stream>>>(bufB, w0, b0, ndst, bufA, stats + 0*512);
    k_bnfin<<<1, 128, 0, stream>>>(stats + 0*512, g0, bt0);
    k_bnapply_bf<<<(NN*64 + 255)/256, 256, 0, stream>>>(bufA, stats + 0*512, nsrc, bufC);

    // ---- layer 1 ----
    k_agg_bf<<<NN, 64, 0, stream>>>(bufC, offsets, degi, csr, bufB);
    k_gemm<128,128,128,true><<<(NN + 63)/64, 256, 0, stream>>>(bufB, w1, b1, ndst, bufA, stats + 1*512);
    k_bnfin<<<1, 128, 0, stream>>>(stats + 1*512, g1, bt1);
    k_bnapply_bf<<<(NN*64 + 255)/256, 256, 0, stream>>>(bufA, stats + 1*512, nsrc, bufC);

    // ---- layer 2 ----
    k_agg_bf<<<NN, 64, 0, stream>>>(bufC, offsets, degi, csr, bufB);
    k_gemm<128,128,128,true><<<(NN + 63)/64, 256, 0, stream>>>(bufB, w2, b2, ndst, bufA, stats + 2*512);
    k_bnfin<<<1, 128, 0, stream>>>(stats + 2*512, g2, bt2);
    k_bnapply_f32<<<(NN*128 + 255)/256, 256, 0, stream>>>(bufA, stats + 2*512);

    // ---- FC: out = x @ wfc + bfc ----
    k_gemm<128,64,128,false><<<(NN + 63)/64, 256, 0, stream>>>(bufA, wfc, bfc, nullptr, out, nullptr);
}

// Round 7
// 531.478 us; speedup vs baseline: 5.9014x; 1.2674x over previous
//
#include <hip/hip_runtime.h>

#define NN 100000
#define NE 1600000
#define BN_EPS 1e-5f
#define BSHIFT 5
#define NBK (NN >> BSHIFT)          // 3125 buckets of exactly 32 nodes
#define NBG (NBK * 8)               // 25000 (bucket,group) cells
#define EPB 16384                   // edges per bucket-block
#define NBLK ((NE + EPB - 1)/EPB)   // 98 scatter blocks
#define CAPG 128                    // slots per (bucket,group) cell
#define CAPB 1024                   // csr slots per bucket = 8*CAPG

typedef short bf16x8 __attribute__((ext_vector_type(8)));
typedef float f32x4  __attribute__((ext_vector_type(4)));

__constant__ float c_wtab[26] = {0.7f,0.9f,0.7f,0.9f,0.3f,0.7f,0.3f,0.9f,0.3f,0.3f,0.9f,0.7f,0.1f,
                                 0.9f,0.5f,0.9f,0.5f,0.5f,0.1f,0.3f,0.7f,0.9f,0.9f,0.9f,0.9f,0.9f};

__device__ __forceinline__ unsigned f2bf(float f){
    unsigned u = __float_as_uint(f);
    return (u + 0x7fffu + ((u >> 16) & 1u)) >> 16;   // round-to-nearest-even
}
__device__ __forceinline__ float bflo(unsigned v){ return __uint_as_float(v << 16); }
__device__ __forceinline__ float bfhi(unsigned v){ return __uint_as_float(v & 0xffff0000u); }

// ---- weight prep: transpose + bf16 (Bt[col][k] layout for MFMA B-operand) ----
__global__ void k_prepw(const float* __restrict__ w0, const float* __restrict__ w1,
                        const float* __restrict__ w2, const float* __restrict__ wfc,
                        unsigned short* __restrict__ wt){
    int i = blockIdx.x*256 + threadIdx.x;
    if (i < 4096){                       // w0t: [128 cols][32 k], k>=26 zero
        int c = i >> 5, k = i & 31;
        float v = (k < 26) ? w0[k*128 + c] : 0.f;
        wt[i] = (unsigned short)f2bf(v);
    } else if (i < 20480){               // w1t: [128][128]
        int j = i - 4096; int c = j >> 7, k = j & 127;
        wt[i] = (unsigned short)f2bf(w1[k*128 + c]);
    } else if (i < 36864){               // w2t: [128][128]
        int j = i - 20480; int c = j >> 7, k = j & 127;
        wt[i] = (unsigned short)f2bf(w2[k*128 + c]);
    } else if (i < 45056){               // wfct: [64][128]
        int j = i - 36864; int c = j >> 7, k = j & 127;
        wt[i] = (unsigned short)f2bf(wfc[k*64 + c]);
    }
}

// ---- bucket scatter with LDS-amortized reservations (dst pairs + src tokens) ----
__global__ __launch_bounds__(512) void k_bucket2(const int* __restrict__ src,
                                                 const int* __restrict__ dst,
                                                 unsigned* __restrict__ gcD,
                                                 unsigned* __restrict__ gcS,
                                                 unsigned* __restrict__ pairsD,
                                                 unsigned* __restrict__ tokS){
    __shared__ unsigned lcD[NBK], lcS[NBK];
    int tid = threadIdx.x;
    for (int i = tid; i < NBK; i += 512){ lcD[i] = 0u; lcS[i] = 0u; }
    __syncthreads();
    int base = blockIdx.x*EPB;
    unsigned g = (unsigned)(blockIdx.x & 7);
    int nEdge = NE - base; if (nEdge > EPB) nEdge = EPB;
    for (int k = tid; k < nEdge; k += 512){
        int e = base + k;
        atomicAdd(&lcD[(unsigned)dst[e] >> BSHIFT], 1u);
        atomicAdd(&lcS[(unsigned)src[e] >> BSHIFT], 1u);
    }
    __syncthreads();
    for (int i = tid; i < NBK; i += 512){
        unsigned c = lcD[i];
        lcD[i] = c ? atomicAdd(&gcD[(unsigned)i*8u + g], c) : 0u;
        c = lcS[i];
        lcS[i] = c ? atomicAdd(&gcS[(unsigned)i*8u + g], c) : 0u;
    }
    __syncthreads();
    for (int k = tid; k < nEdge; k += 512){
        int e = base + k;
        int d = dst[e], s = src[e];
        unsigned pd = atomicAdd(&lcD[(unsigned)d >> BSHIFT], 1u);
        if (pd < CAPG)
            pairsD[((size_t)((unsigned)d >> BSHIFT)*8u + g)*CAPG + pd] =
                ((unsigned)(d & 31) << 17) | (unsigned)s;
        unsigned ps = atomicAdd(&lcS[(unsigned)s >> BSHIFT], 1u);
        if (ps < CAPG)
            tokS[((size_t)((unsigned)s >> BSHIFT)*8u + g)*CAPG + ps] = (unsigned)(s & 31);
    }
}

// ---- block-per-bucket: CSR build + degi + dego, zero global atomics ----
__global__ __launch_bounds__(256) void k_fill4(const unsigned* __restrict__ gcD,
                                               const unsigned* __restrict__ gcS,
                                               const unsigned* __restrict__ pairsD,
                                               const unsigned* __restrict__ tokS,
                                               int* __restrict__ csr,
                                               unsigned* __restrict__ offs,
                                               unsigned* __restrict__ degi,
                                               unsigned* __restrict__ dego){
    __shared__ unsigned cnt[32], cur[32], scnt[32], gnD[8], gnS[8];
    int b = blockIdx.x, tid = threadIdx.x;
    if (tid < 32){ cnt[tid] = 0u; scnt[tid] = 0u; }
    if (tid < 8){
        unsigned n = gcD[b*8 + tid]; gnD[tid] = n > CAPG ? CAPG : n;
        n = gcS[b*8 + tid];          gnS[tid] = n > CAPG ? CAPG : n;
    }
    __syncthreads();
    int w = tid >> 6, lane = tid & 63;
    #pragma unroll
    for (int gg = 0; gg < 2; ++gg){
        int g = w + gg*4;
        {
            unsigned n = gnD[g];
            const unsigned* P = pairsD + ((size_t)b*8 + g)*CAPG;
            for (unsigned i = lane; i < n; i += 64)
                atomicAdd(&cnt[P[i] >> 17], 1u);
        }
        {
            unsigned n = gnS[g];
            const unsigned* T = tokS + ((size_t)b*8 + g)*CAPG;
            for (unsigned i = lane; i < n; i += 64)
                atomicAdd(&scnt[T[i] & 31], 1u);
        }
    }
    __syncthreads();
    if (tid == 0){
        unsigned run = 0;
        #pragma unroll
        for (int i = 0; i < 32; ++i){ cur[i] = run; run += cnt[i]; }
    }
    __syncthreads();
    if (tid < 32){
        offs[(b << BSHIFT) + tid] = (unsigned)(b*CAPB) + cur[tid];
        degi[(b << BSHIFT) + tid] = cnt[tid];
        dego[(b << BSHIFT) + tid] = scnt[tid];
    }
    __syncthreads();
    #pragma unroll
    for (int gg = 0; gg < 2; ++gg){
        int g = w + gg*4;
        unsigned n = gnD[g];
        const unsigned* P = pairsD + ((size_t)b*8 + g)*CAPG;
        for (unsigned i = lane; i < n; i += 64){
            unsigned pr = P[i];
            unsigned p = atomicAdd(&cur[pr >> 17], 1u);
            csr[(size_t)b*CAPB + p] = (int)(pr & 0x1FFFFu);
        }
    }
}

// ---------------- per-node: norms + argmax weight + xn0 = h*nsrc (padded [N,32]) ----------------
__global__ void k_node(const float* __restrict__ h, const unsigned* __restrict__ dego,
                       const unsigned* __restrict__ degi, float* __restrict__ nsrc,
                       float* __restrict__ ndst, float* __restrict__ outw,
                       float* __restrict__ xn0){
    int i = blockIdx.x*blockDim.x + threadIdx.x;
    if (i < NN){
        float d0 = (float)dego[i]; d0 = d0 < 1.f ? 1.f : d0;
        float d1 = (float)degi[i]; d1 = d1 < 1.f ? 1.f : d1;
        float ns = rsqrtf(d0);
        nsrc[i] = ns;
        ndst[i] = rsqrtf(d1);
        float row[26];
        #pragma unroll
        for (int c = 0; c < 26; ++c) row[c] = h[(size_t)i*26 + c];
        float best = row[0]; int bi = 0;
        #pragma unroll
        for (int c = 1; c < 26; ++c){ if (row[c] > best){ best = row[c]; bi = c; } }
        outw[i] = c_wtab[bi];
        #pragma unroll
        for (int c = 0; c < 26; ++c) xn0[(size_t)i*32 + c] = row[c]*ns;
        #pragma unroll
        for (int c = 26; c < 32; ++c) xn0[(size_t)i*32 + c] = 0.f;
    }
}

// ---------------- layer-0 aggregation -> bf16 [N,32] ----------------
__global__ __launch_bounds__(64) void k_agg0(const float* __restrict__ xn,
                                             const unsigned* __restrict__ offs,
                                             const unsigned* __restrict__ degi,
                                             const int* __restrict__ csr,
                                             unsigned short* __restrict__ agg){
    int node = blockIdx.x*2 + (threadIdx.x >> 5);
    int c = threadIdx.x & 31;
    unsigned beg = offs[node], end = beg + degi[node];
    float acc = 0.f;
    unsigned e = beg;
    for (; e + 4 <= end; e += 4){
        int s0 = csr[e+0], s1 = csr[e+1], s2 = csr[e+2], s3 = csr[e+3];
        float a0 = xn[(size_t)s0*32 + c];
        float a1 = xn[(size_t)s1*32 + c];
        float a2 = xn[(size_t)s2*32 + c];
        float a3 = xn[(size_t)s3*32 + c];
        acc += (a0 + a1) + (a2 + a3);
    }
    for (; e < end; ++e)
        acc += xn[(size_t)csr[e]*32 + c];
    agg[(size_t)node*32 + c] = (unsigned short)f2bf(acc);
}

// ---------------- layers 1/2 aggregation: bf16 gather -> bf16 [N,128] ----------------
__global__ __launch_bounds__(64) void k_agg_bf(const unsigned* __restrict__ xn,
                                               const unsigned* __restrict__ offs,
                                               const unsigned* __restrict__ degi,
                                               const int* __restrict__ csr,
                                               unsigned* __restrict__ agg){
    int node = blockIdx.x;
    int t = threadIdx.x;   // dword t = channels (2t, 2t+1)
    unsigned beg = offs[node], end = beg + degi[node];
    float a0 = 0.f, a1 = 0.f;
    unsigned e = beg;
    for (; e + 8 <= end; e += 8){
        int s[8];
        #pragma unroll
        for (int i = 0; i < 8; ++i) s[i] = csr[e + i];
        #pragma unroll
        for (int i = 0; i < 8; ++i){
            unsigned v = xn[(size_t)s[i]*64 + t];
            a0 += bflo(v);
            a1 += bfhi(v);
        }
    }
    for (; e < end; ++e){
        unsigned v = xn[(size_t)csr[e]*64 + t];
        a0 += bflo(v);
        a1 += bfhi(v);
    }
    agg[(size_t)node*64 + t] = f2bf(a0) | (f2bf(a1) << 16);
}

// ---------------- MFMA GEMM: Z = A(bf16) @ Bt^T (*ndst) + bias, fused BN stats ----------------
// A: [NN][CIN] bf16 row-major; Bt: [COUT][CIN] bf16 (pre-transposed weights)
template<int CIN, int COUT, bool STATS, bool NDST>
__global__ __launch_bounds__(256) void k_gemm_mfma(const unsigned short* __restrict__ A,
                                                   const unsigned short* __restrict__ Bt,
                                                   const float* __restrict__ bias,
                                                   const float* __restrict__ ndst,
                                                   float* __restrict__ Z,
                                                   float* __restrict__ stats){
    constexpr int KD = CIN/2;     // dwords per row
    constexpr int NT = COUT/16;   // 16-col tiles per wave
    __shared__ char sA[64*CIN*2];
    __shared__ char sB[COUT*CIN*2];
    __shared__ float sS[2][COUT];
    const int tid = threadIdx.x;
    const int row0 = blockIdx.x*64;
    // stage A (bf16, XOR-swizzled rows)
    const unsigned* Ad = (const unsigned*)A;
    for (int i = tid; i < 64*KD; i += 256){
        int r = i/KD, c2 = i - r*KD;
        int gr = row0 + r;
        unsigned v = (gr < NN) ? Ad[(size_t)gr*KD + c2] : 0u;
        *(unsigned*)(sA + ((r*CIN*2 + c2*4) ^ ((r&7)<<4))) = v;
    }
    // stage Bt (bf16, same swizzle keyed on col)
    const unsigned* Bd = (const unsigned*)Bt;
    for (int i = tid; i < COUT*KD; i += 256){
        int cc = i/KD, c2 = i - cc*KD;
        *(unsigned*)(sB + ((cc*CIN*2 + c2*4) ^ ((cc&7)<<4))) = Bd[i];
    }
    if (STATS){
        for (int i = tid; i < 2*COUT; i += 256) (&sS[0][0])[i] = 0.f;
    }
    __syncthreads();
    const int w = tid >> 6, lane = tid & 63;
    const int lrow = lane & 15, kg = lane >> 4;
    f32x4 acc[NT];
    #pragma unroll
    for (int n = 0; n < NT; ++n) acc[n] = (f32x4){0.f,0.f,0.f,0.f};
    const int arow = w*16 + lrow;
    #pragma unroll
    for (int kk = 0; kk < CIN/32; ++kk){
        const int kb = kk*64 + kg*16;
        bf16x8 af = *(const bf16x8*)(sA + ((arow*CIN*2 + kb) ^ ((arow&7)<<4)));
        #pragma unroll
        for (int n = 0; n < NT; ++n){
            int bc = n*16 + lrow;
            bf16x8 bv = *(const bf16x8*)(sB + ((bc*CIN*2 + kb) ^ ((bc&7)<<4)));
            acc[n] = __builtin_amdgcn_mfma_f32_16x16x32_bf16(af, bv, acc[n], 0, 0, 0);
        }
    }
    // epilogue: C/D mapping col=lane&15, row=(lane>>4)*4+j  [m89-verified]
    int grow[4]; float nm[4]; bool val[4];
    #pragma unroll
    for (int j = 0; j < 4; ++j){
        grow[j] = row0 + w*16 + kg*4 + j;
        val[j]  = grow[j] < NN;
        nm[j]   = (NDST && val[j]) ? ndst[grow[j]] : 1.f;
    }
    #pragma unroll
    for (int n = 0; n < NT; ++n){
        int gcol = n*16 + lrow;
        float bv = bias[gcol];
        float cs = 0.f, cq = 0.f;
        #pragma unroll
        for (int j = 0; j < 4; ++j){
            float z = acc[n][j]*nm[j] + bv;
            if (val[j]){
                Z[(size_t)grow[j]*COUT + gcol] = z;
                if (STATS){ cs += z; cq += z*z; }
            }
        }
        if (STATS){
            cs += __shfl_xor(cs, 16); cs += __shfl_xor(cs, 32);
            cq += __shfl_xor(cq, 16); cq += __shfl_xor(cq, 32);
            if (kg == 0){
                atomicAdd(&sS[0][gcol], cs);
                atomicAdd(&sS[1][gcol], cq);
            }
        }
    }
    if (STATS){
        __syncthreads();
        for (int i = tid; i < COUT; i += 256){
            atomicAdd(&stats[i],       sS[0][i]);
            atomicAdd(&stats[128 + i], sS[1][i]);
        }
    }
}

// ---------------- BN finalize: scale/shift ----------------
__global__ void k_bnfin(float* __restrict__ stats, const float* __restrict__ g,
                        const float* __restrict__ bt){
    int c = threadIdx.x;  // 128
    float mu  = stats[c] / (float)NN;
    float var = stats[128 + c] / (float)NN - mu*mu;
    if (var < 0.f) var = 0.f;
    float sc = g[c] * rsqrtf(var + BN_EPS);
    stats[256 + c] = sc;
    stats[384 + c] = bt[c] - mu*sc;
}

// ---------------- BN apply + ReLU (+ optional *nsrc) -> bf16 [N,128] ----------------
__global__ void k_bnapply_bf(const float* __restrict__ X, const float* __restrict__ stats,
                             const float* __restrict__ nsrc, unsigned* __restrict__ out){
    int idx = blockIdx.x*blockDim.x + threadIdx.x;
    if (idx < NN*64){
        int d = idx & 63;
        int node = idx >> 6;
        int c0 = d << 1;
        float2 x = reinterpret_cast<const float2*>(X)[idx];
        float v0 = x.x*stats[256 + c0]     + stats[384 + c0];
        float v1 = x.y*stats[256 + c0 + 1] + stats[384 + c0 + 1];
        float ns = nsrc ? nsrc[node] : 1.f;
        v0 = v0 > 0.f ? v0*ns : 0.f;
        v1 = v1 > 0.f ? v1*ns : 0.f;
        out[idx] = f2bf(v0) | (f2bf(v1) << 16);
    }
}

extern "C" void kernel_launch(void* const* d_in, const int* in_sizes, int n_in,
                              void* d_out, int out_size, void* d_ws, size_t ws_size,
                              hipStream_t stream) {
    const float* h   = (const float*)d_in[0];
    const int*   src = (const int*)d_in[1];
    const int*   dst = (const int*)d_in[2];
    const float* w0  = (const float*)d_in[3];
    const float* b0  = (const float*)d_in[4];
    const float* w1  = (const float*)d_in[5];
    const float* b1  = (const float*)d_in[6];
    const float* w2  = (const float*)d_in[7];
    const float* b2  = (const float*)d_in[8];
    const float* g0  = (const float*)d_in[9];
    const float* bt0 = (const float*)d_in[10];
    const float* g1  = (const float*)d_in[11];
    const float* bt1 = (const float*)d_in[12];
    const float* g2  = (const float*)d_in[13];
    const float* bt2 = (const float*)d_in[14];
    const float* wfc = (const float*)d_in[15];
    const float* bfc = (const float*)d_in[16];

    float* out   = (float*)d_out;                     // [NN,64]
    float* out_w = out + (size_t)NN*64;               // [NN,1]

    char* ws = (char*)d_ws;
    size_t off = 0;
    auto alloc = [&](size_t b){ size_t p = off; off += (b + 255) & ~(size_t)255; return ws + p; };

    unsigned*       dego    = (unsigned*)alloc((size_t)NN*4);
    unsigned*       degi    = (unsigned*)alloc((size_t)NN*4);
    float*          nsrc    = (float*)   alloc((size_t)NN*4);
    float*          ndst    = (float*)   alloc((size_t)NN*4);
    unsigned*       offsets = (unsigned*)alloc((size_t)NN*4);
    unsigned*       gcD     = (unsigned*)alloc((size_t)NBG*4);
    unsigned*       gcS     = (unsigned*)alloc((size_t)NBG*4);
    float*          stats   = (float*)   alloc(3*512*4);
    unsigned short* wt      = (unsigned short*)alloc(45056*2);  // bf16 transposed weights
    int*            csr     = (int*)     alloc((size_t)NBK*CAPB*4);
    float*          xn0     = (float*)   alloc((size_t)NN*32*4);
    float*          bufA    = (float*)   alloc((size_t)NN*128*4);   // GEMM out (fp32)
    float*          bufB    = (float*)   alloc((size_t)NN*128*4);   // agg out bf16 / pairs alias
    unsigned*       bufC    = (unsigned*)alloc((size_t)NN*64*4);    // bf16 features
    (void)ws_size; (void)in_sizes; (void)n_in; (void)out_size;

    unsigned* pairsD = (unsigned*)bufB;                        // 12.8 MB
    unsigned* tokS   = (unsigned*)bufB + (size_t)NBG*CAPG;     // 12.8 MB, dead after k_fill4
    unsigned short* aggB = (unsigned short*)bufB;              // bf16 agg output

    hipMemsetAsync(gcD, 0, (size_t)NBG*4, stream);
    hipMemsetAsync(gcS, 0, (size_t)NBG*4, stream);
    hipMemsetAsync(stats, 0, 3*512*4, stream);

    const int GB = (NN + 63)/64;   // 1563 GEMM blocks

    // ---- build ----
    k_prepw<<<176, 256, 0, stream>>>(w0, w1, w2, wfc, wt);
    k_bucket2<<<NBLK, 512, 0, stream>>>(src, dst, gcD, gcS, pairsD, tokS);
    k_fill4<<<NBK, 256, 0, stream>>>(gcD, gcS, pairsD, tokS, csr, offsets, degi, dego);
    k_node<<<(NN + 255)/256, 256, 0, stream>>>(h, dego, degi, nsrc, ndst, out_w, xn0);

    // ---- layer 0 ----
    k_agg0<<<NN/2, 64, 0, stream>>>(xn0, offsets, degi, csr, aggB);
    k_gemm_mfma<32,128,true,true><<<GB, 256, 0, stream>>>(aggB, wt, b0, ndst, bufA, stats + 0*512);
    k_bnfin<<<1, 128, 0, stream>>>(stats + 0*512, g0, bt0);
    k_bnapply_bf<<<(NN*64 + 255)/256, 256, 0, stream>>>(bufA, stats + 0*512, nsrc, bufC);

    // ---- layer 1 ----
    k_agg_bf<<<NN, 64, 0, stream>>>(bufC, offsets, degi, csr, (unsigned*)aggB);
    k_gemm_mfma<128,128,true,true><<<GB, 256, 0, stream>>>(aggB, wt + 4096, b1, ndst, bufA, stats + 1*512);
    k_bnfin<<<1, 128, 0, stream>>>(stats + 1*512, g1, bt1);
    k_bnapply_bf<<<(NN*64 + 255)/256, 256, 0, stream>>>(bufA, stats + 1*512, nsrc, bufC);

    // ---- layer 2 ----
    k_agg_bf<<<NN, 64, 0, stream>>>(bufC, offsets, degi, csr, (unsigned*)aggB);
    k_gemm_mfma<128,128,true,true><<<GB, 256, 0, stream>>>(aggB, wt + 20480, b2, ndst, bufA, stats + 2*512);
    k_bnfin<<<1, 128, 0, stream>>>(stats + 2*512, g2, bt2);
    k_bnapply_bf<<<(NN*64 + 255)/256, 256, 0, stream>>>(bufA, stats + 2*512, nullptr, bufC);

    // ---- FC: out = x @ wfc + bfc ----
    k_gemm_mfma<128,64,false,false><<<GB, 256, 0, stream>>>((unsigned short*)bufC, wt + 36864, bfc,
                                                            nullptr, out, nullptr);
}

// Round 8
// 531.357 us; speedup vs baseline: 5.9028x; 1.0002x over previous
//
#include <hip/hip_runtime.h>

#define NN 100000
#define NE 1600000
#define BN_EPS 1e-5f
#define BSHIFT 5
#define NBK (NN >> BSHIFT)          // 3125 buckets of exactly 32 nodes
#define NBG (NBK * 8)               // 25000 (bucket,group) cells
#define EPB 4096                    // edges per bucket-block (391 blocks -> ~12 waves/CU)
#define NBLK ((NE + EPB - 1)/EPB)
#define CAPG 128                    // slots per (bucket,group) cell (mean 64)
#define CAPB 1024                   // csr slots per bucket = 8*CAPG

typedef short bf16x8 __attribute__((ext_vector_type(8)));
typedef float f32x4  __attribute__((ext_vector_type(4)));

__constant__ float c_wtab[26] = {0.7f,0.9f,0.7f,0.9f,0.3f,0.7f,0.3f,0.9f,0.3f,0.3f,0.9f,0.7f,0.1f,
                                 0.9f,0.5f,0.9f,0.5f,0.5f,0.1f,0.3f,0.7f,0.9f,0.9f,0.9f,0.9f,0.9f};

__device__ __forceinline__ unsigned f2bf(float f){
    unsigned u = __float_as_uint(f);
    return (u + 0x7fffu + ((u >> 16) & 1u)) >> 16;   // round-to-nearest-even
}
__device__ __forceinline__ float bflo(unsigned v){ return __uint_as_float(v << 16); }
__device__ __forceinline__ float bfhi(unsigned v){ return __uint_as_float(v & 0xffff0000u); }

// ---- weight prep: transpose + bf16 (Bt[col][k] layout for MFMA B-operand) ----
__global__ void k_prepw(const float* __restrict__ w0, const float* __restrict__ w1,
                        const float* __restrict__ w2, const float* __restrict__ wfc,
                        unsigned short* __restrict__ wt){
    int i = blockIdx.x*256 + threadIdx.x;
    if (i < 4096){                       // w0t: [128 cols][32 k], k>=26 zero
        int c = i >> 5, k = i & 31;
        float v = (k < 26) ? w0[k*128 + c] : 0.f;
        wt[i] = (unsigned short)f2bf(v);
    } else if (i < 20480){               // w1t: [128][128]
        int j = i - 4096; int c = j >> 7, k = j & 127;
        wt[i] = (unsigned short)f2bf(w1[k*128 + c]);
    } else if (i < 36864){               // w2t: [128][128]
        int j = i - 20480; int c = j >> 7, k = j & 127;
        wt[i] = (unsigned short)f2bf(w2[k*128 + c]);
    } else if (i < 45056){               // wfct: [64][128]
        int j = i - 36864; int c = j >> 7, k = j & 127;
        wt[i] = (unsigned short)f2bf(wfc[k*64 + c]);
    }
}

// ---- bucket scatter with LDS-amortized reservations (dst pairs + src tokens) ----
__global__ __launch_bounds__(512) void k_bucket2(const int* __restrict__ src,
                                                 const int* __restrict__ dst,
                                                 unsigned* __restrict__ gcD,
                                                 unsigned* __restrict__ gcS,
                                                 unsigned* __restrict__ pairsD,
                                                 unsigned* __restrict__ tokS){
    __shared__ unsigned lcD[NBK], lcS[NBK];
    int tid = threadIdx.x;
    for (int i = tid; i < NBK; i += 512){ lcD[i] = 0u; lcS[i] = 0u; }
    __syncthreads();
    int base = blockIdx.x*EPB;
    unsigned g = (unsigned)(blockIdx.x & 7);
    int nEdge = NE - base; if (nEdge > EPB) nEdge = EPB;
    for (int k = tid; k < nEdge; k += 512){
        int e = base + k;
        atomicAdd(&lcD[(unsigned)dst[e] >> BSHIFT], 1u);
        atomicAdd(&lcS[(unsigned)src[e] >> BSHIFT], 1u);
    }
    __syncthreads();
    for (int i = tid; i < NBK; i += 512){
        unsigned c = lcD[i];
        lcD[i] = c ? atomicAdd(&gcD[(unsigned)i*8u + g], c) : 0u;
        c = lcS[i];
        lcS[i] = c ? atomicAdd(&gcS[(unsigned)i*8u + g], c) : 0u;
    }
    __syncthreads();
    for (int k = tid; k < nEdge; k += 512){
        int e = base + k;
        int d = dst[e], s = src[e];
        unsigned pd = atomicAdd(&lcD[(unsigned)d >> BSHIFT], 1u);
        if (pd < CAPG)
            pairsD[((size_t)((unsigned)d >> BSHIFT)*8u + g)*CAPG + pd] =
                ((unsigned)(d & 31) << 17) | (unsigned)s;
        unsigned ps = atomicAdd(&lcS[(unsigned)s >> BSHIFT], 1u);
        if (ps < CAPG)
            tokS[((size_t)((unsigned)s >> BSHIFT)*8u + g)*CAPG + ps] = (unsigned)(s & 31);
    }
}

// ---- block-per-bucket: CSR build + degi + dego, zero global atomics ----
__global__ __launch_bounds__(256) void k_fill4(const unsigned* __restrict__ gcD,
                                               const unsigned* __restrict__ gcS,
                                               const unsigned* __restrict__ pairsD,
                                               const unsigned* __restrict__ tokS,
                                               int* __restrict__ csr,
                                               unsigned* __restrict__ offs,
                                               unsigned* __restrict__ degi,
                                               unsigned* __restrict__ dego){
    __shared__ unsigned cnt[32], cur[32], scnt[32], gnD[8], gnS[8];
    int b = blockIdx.x, tid = threadIdx.x;
    if (tid < 32){ cnt[tid] = 0u; scnt[tid] = 0u; }
    if (tid < 8){
        unsigned n = gcD[b*8 + tid]; gnD[tid] = n > CAPG ? CAPG : n;
        n = gcS[b*8 + tid];          gnS[tid] = n > CAPG ? CAPG : n;
    }
    __syncthreads();
    int w = tid >> 6, lane = tid & 63;
    #pragma unroll
    for (int gg = 0; gg < 2; ++gg){
        int g = w + gg*4;
        {
            unsigned n = gnD[g];
            const unsigned* P = pairsD + ((size_t)b*8 + g)*CAPG;
            for (unsigned i = lane; i < n; i += 64)
                atomicAdd(&cnt[P[i] >> 17], 1u);
        }
        {
            unsigned n = gnS[g];
            const unsigned* T = tokS + ((size_t)b*8 + g)*CAPG;
            for (unsigned i = lane; i < n; i += 64)
                atomicAdd(&scnt[T[i] & 31], 1u);
        }
    }
    __syncthreads();
    if (tid == 0){
        unsigned run = 0;
        #pragma unroll
        for (int i = 0; i < 32; ++i){ cur[i] = run; run += cnt[i]; }
    }
    __syncthreads();
    if (tid < 32){
        offs[(b << BSHIFT) + tid] = (unsigned)(b*CAPB) + cur[tid];
        degi[(b << BSHIFT) + tid] = cnt[tid];
        dego[(b << BSHIFT) + tid] = scnt[tid];
    }
    __syncthreads();
    #pragma unroll
    for (int gg = 0; gg < 2; ++gg){
        int g = w + gg*4;
        unsigned n = gnD[g];
        const unsigned* P = pairsD + ((size_t)b*8 + g)*CAPG;
        for (unsigned i = lane; i < n; i += 64){
            unsigned pr = P[i];
            unsigned p = atomicAdd(&cur[pr >> 17], 1u);
            csr[(size_t)b*CAPB + p] = (int)(pr & 0x1FFFFu);
        }
    }
}

// ---------------- per-node: norms + argmax weight + xn0 = h*nsrc (padded [N,32]) ----------------
__global__ void k_node(const float* __restrict__ h, const unsigned* __restrict__ dego,
                       const unsigned* __restrict__ degi, float* __restrict__ nsrc,
                       float* __restrict__ ndst, float* __restrict__ outw,
                       float* __restrict__ xn0){
    int i = blockIdx.x*blockDim.x + threadIdx.x;
    if (i < NN){
        float d0 = (float)dego[i]; d0 = d0 < 1.f ? 1.f : d0;
        float d1 = (float)degi[i]; d1 = d1 < 1.f ? 1.f : d1;
        float ns = rsqrtf(d0);
        nsrc[i] = ns;
        ndst[i] = rsqrtf(d1);
        float row[26];
        #pragma unroll
        for (int c = 0; c < 26; ++c) row[c] = h[(size_t)i*26 + c];
        float best = row[0]; int bi = 0;
        #pragma unroll
        for (int c = 1; c < 26; ++c){ if (row[c] > best){ best = row[c]; bi = c; } }
        outw[i] = c_wtab[bi];
        #pragma unroll
        for (int c = 0; c < 26; ++c) xn0[(size_t)i*32 + c] = row[c]*ns;
        #pragma unroll
        for (int c = 26; c < 32; ++c) xn0[(size_t)i*32 + c] = 0.f;
    }
}

// ---------------- layer-0 aggregation -> bf16 [N,32] ----------------
__global__ __launch_bounds__(64) void k_agg0(const float* __restrict__ xn,
                                             const unsigned* __restrict__ offs,
                                             const unsigned* __restrict__ degi,
                                             const int* __restrict__ csr,
                                             unsigned short* __restrict__ agg){
    int node = blockIdx.x*2 + (threadIdx.x >> 5);
    int c = threadIdx.x & 31;
    unsigned beg = offs[node], end = beg + degi[node];
    float acc = 0.f;
    unsigned e = beg;
    for (; e + 4 <= end; e += 4){
        int s0 = csr[e+0], s1 = csr[e+1], s2 = csr[e+2], s3 = csr[e+3];
        float a0 = xn[(size_t)s0*32 + c];
        float a1 = xn[(size_t)s1*32 + c];
        float a2 = xn[(size_t)s2*32 + c];
        float a3 = xn[(size_t)s3*32 + c];
        acc += (a0 + a1) + (a2 + a3);
    }
    for (; e < end; ++e)
        acc += xn[(size_t)csr[e]*32 + c];
    agg[(size_t)node*32 + c] = (unsigned short)f2bf(acc);
}

// ---------------- layers 1/2 aggregation: bf16 gather -> bf16 [N,128] ----------------
__global__ __launch_bounds__(64) void k_agg_bf(const unsigned* __restrict__ xn,
                                               const unsigned* __restrict__ offs,
                                               const unsigned* __restrict__ degi,
                                               const int* __restrict__ csr,
                                               unsigned* __restrict__ agg){
    int node = blockIdx.x;
    int t = threadIdx.x;   // dword t = channels (2t, 2t+1)
    unsigned beg = offs[node], end = beg + degi[node];
    float a0 = 0.f, a1 = 0.f;
    unsigned e = beg;
    for (; e + 8 <= end; e += 8){
        int s[8];
        #pragma unroll
        for (int i = 0; i < 8; ++i) s[i] = csr[e + i];
        #pragma unroll
        for (int i = 0; i < 8; ++i){
            unsigned v = xn[(size_t)s[i]*64 + t];
            a0 += bflo(v);
            a1 += bfhi(v);
        }
    }
    for (; e < end; ++e){
        unsigned v = xn[(size_t)csr[e]*64 + t];
        a0 += bflo(v);
        a1 += bfhi(v);
    }
    agg[(size_t)node*64 + t] = f2bf(a0) | (f2bf(a1) << 16);
}

// ---------------- MFMA GEMM: Z = A(bf16) @ Bt^T (*ndst) + bias, fused BN stats ----------------
// A: [NN][CIN] bf16 row-major; Bt: [COUT][CIN] bf16. Z: bf16 (pre-BN) or fp32 (FC).
template<int CIN, int COUT, bool STATS, bool NDST, bool F32OUT>
__global__ __launch_bounds__(256) void k_gemm_mfma(const unsigned short* __restrict__ A,
                                                   const unsigned short* __restrict__ Bt,
                                                   const float* __restrict__ bias,
                                                   const float* __restrict__ ndst,
                                                   void* __restrict__ Zv,
                                                   float* __restrict__ stats){
    constexpr int KD = CIN/2;     // dwords per row
    constexpr int NT = COUT/16;   // 16-col tiles per wave
    __shared__ char sA[64*CIN*2];
    __shared__ char sB[COUT*CIN*2];
    __shared__ float sS[2][COUT];
    float* Zf = (float*)Zv;
    unsigned short* Zh = (unsigned short*)Zv;
    const int tid = threadIdx.x;
    const int row0 = blockIdx.x*64;
    // stage A (bf16, XOR-swizzled rows)
    const unsigned* Ad = (const unsigned*)A;
    for (int i = tid; i < 64*KD; i += 256){
        int r = i/KD, c2 = i - r*KD;
        int gr = row0 + r;
        unsigned v = (gr < NN) ? Ad[(size_t)gr*KD + c2] : 0u;
        *(unsigned*)(sA + ((r*CIN*2 + c2*4) ^ ((r&7)<<4))) = v;
    }
    // stage Bt (bf16, same swizzle keyed on col)
    const unsigned* Bd = (const unsigned*)Bt;
    for (int i = tid; i < COUT*KD; i += 256){
        int cc = i/KD, c2 = i - cc*KD;
        *(unsigned*)(sB + ((cc*CIN*2 + c2*4) ^ ((cc&7)<<4))) = Bd[i];
    }
    if (STATS){
        for (int i = tid; i < 2*COUT; i += 256) (&sS[0][0])[i] = 0.f;
    }
    __syncthreads();
    const int w = tid >> 6, lane = tid & 63;
    const int lrow = lane & 15, kg = lane >> 4;
    f32x4 acc[NT];
    #pragma unroll
    for (int n = 0; n < NT; ++n) acc[n] = (f32x4){0.f,0.f,0.f,0.f};
    const int arow = w*16 + lrow;
    #pragma unroll
    for (int kk = 0; kk < CIN/32; ++kk){
        const int kb = kk*64 + kg*16;
        bf16x8 af = *(const bf16x8*)(sA + ((arow*CIN*2 + kb) ^ ((arow&7)<<4)));
        #pragma unroll
        for (int n = 0; n < NT; ++n){
            int bc = n*16 + lrow;
            bf16x8 bv = *(const bf16x8*)(sB + ((bc*CIN*2 + kb) ^ ((bc&7)<<4)));
            acc[n] = __builtin_amdgcn_mfma_f32_16x16x32_bf16(af, bv, acc[n], 0, 0, 0);
        }
    }
    // epilogue: C/D mapping col=lane&15, row=(lane>>4)*4+j  [m89-verified]
    int grow[4]; float nm[4]; bool val[4];
    #pragma unroll
    for (int j = 0; j < 4; ++j){
        grow[j] = row0 + w*16 + kg*4 + j;
        val[j]  = grow[j] < NN;
        nm[j]   = (NDST && val[j]) ? ndst[grow[j]] : 1.f;
    }
    #pragma unroll
    for (int n = 0; n < NT; ++n){
        int gcol = n*16 + lrow;
        float bv = bias[gcol];
        float cs = 0.f, cq = 0.f;
        #pragma unroll
        for (int j = 0; j < 4; ++j){
            float z = acc[n][j]*nm[j] + bv;
            if (val[j]){
                if (F32OUT) Zf[(size_t)grow[j]*COUT + gcol] = z;
                else        Zh[(size_t)grow[j]*COUT + gcol] = (unsigned short)f2bf(z);
                if (STATS){ cs += z; cq += z*z; }
            }
        }
        if (STATS){
            cs += __shfl_xor(cs, 16); cs += __shfl_xor(cs, 32);
            cq += __shfl_xor(cq, 16); cq += __shfl_xor(cq, 32);
            if (kg == 0){
                atomicAdd(&sS[0][gcol], cs);
                atomicAdd(&sS[1][gcol], cq);
            }
        }
    }
    if (STATS){
        __syncthreads();
        for (int i = tid; i < COUT; i += 256){
            atomicAdd(&stats[i],       sS[0][i]);
            atomicAdd(&stats[128 + i], sS[1][i]);
        }
    }
}

// ---------------- BN finalize: scale/shift ----------------
__global__ void k_bnfin(float* __restrict__ stats, const float* __restrict__ g,
                        const float* __restrict__ bt){
    int c = threadIdx.x;  // 128
    float mu  = stats[c] / (float)NN;
    float var = stats[128 + c] / (float)NN - mu*mu;
    if (var < 0.f) var = 0.f;
    float sc = g[c] * rsqrtf(var + BN_EPS);
    stats[256 + c] = sc;
    stats[384 + c] = bt[c] - mu*sc;
}

// ---------------- BN apply + ReLU (+ optional *nsrc): bf16 Z -> bf16 features ----------------
__global__ void k_bnapply_bf(const unsigned* __restrict__ Xb, const float* __restrict__ stats,
                             const float* __restrict__ nsrc, unsigned* __restrict__ out){
    int idx = blockIdx.x*blockDim.x + threadIdx.x;
    if (idx < NN*64){
        int d = idx & 63;
        int node = idx >> 6;
        int c0 = d << 1;
        unsigned v = Xb[idx];            // bf16 pair: cols (2d, 2d+1)
        float v0 = bflo(v)*stats[256 + c0]     + stats[384 + c0];
        float v1 = bfhi(v)*stats[256 + c0 + 1] + stats[384 + c0 + 1];
        float ns = nsrc ? nsrc[node] : 1.f;
        v0 = v0 > 0.f ? v0*ns : 0.f;
        v1 = v1 > 0.f ? v1*ns : 0.f;
        out[idx] = f2bf(v0) | (f2bf(v1) << 16);
    }
}

extern "C" void kernel_launch(void* const* d_in, const int* in_sizes, int n_in,
                              void* d_out, int out_size, void* d_ws, size_t ws_size,
                              hipStream_t stream) {
    const float* h   = (const float*)d_in[0];
    const int*   src = (const int*)d_in[1];
    const int*   dst = (const int*)d_in[2];
    const float* w0  = (const float*)d_in[3];
    const float* b0  = (const float*)d_in[4];
    const float* w1  = (const float*)d_in[5];
    const float* b1  = (const float*)d_in[6];
    const float* w2  = (const float*)d_in[7];
    const float* b2  = (const float*)d_in[8];
    const float* g0  = (const float*)d_in[9];
    const float* bt0 = (const float*)d_in[10];
    const float* g1  = (const float*)d_in[11];
    const float* bt1 = (const float*)d_in[12];
    const float* g2  = (const float*)d_in[13];
    const float* bt2 = (const float*)d_in[14];
    const float* wfc = (const float*)d_in[15];
    const float* bfc = (const float*)d_in[16];

    float* out   = (float*)d_out;                     // [NN,64]
    float* out_w = out + (size_t)NN*64;               // [NN,1]

    char* ws = (char*)d_ws;
    size_t off = 0;
    auto alloc = [&](size_t b){ size_t p = off; off += (b + 255) & ~(size_t)255; return ws + p; };

    unsigned*       dego    = (unsigned*)alloc((size_t)NN*4);
    unsigned*       degi    = (unsigned*)alloc((size_t)NN*4);
    float*          nsrc    = (float*)   alloc((size_t)NN*4);
    float*          ndst    = (float*)   alloc((size_t)NN*4);
    unsigned*       offsets = (unsigned*)alloc((size_t)NN*4);
    unsigned*       gcD     = (unsigned*)alloc((size_t)NBG*4);
    unsigned*       gcS     = (unsigned*)alloc((size_t)NBG*4);
    float*          stats   = (float*)   alloc(3*512*4);
    unsigned short* wt      = (unsigned short*)alloc(45056*2);  // bf16 transposed weights
    int*            csr     = (int*)     alloc((size_t)NBK*CAPB*4);
    float*          xn0     = (float*)   alloc((size_t)NN*32*4);
    unsigned short* bufA    = (unsigned short*)alloc((size_t)NN*128*2); // GEMM out (bf16 pre-BN)
    float*          bufB    = (float*)   alloc((size_t)NN*128*4);   // agg out bf16 / pairs alias
    unsigned*       bufC    = (unsigned*)alloc((size_t)NN*64*4);    // bf16 features
    (void)ws_size; (void)in_sizes; (void)n_in; (void)out_size;

    unsigned* pairsD = (unsigned*)bufB;                        // 12.8 MB
    unsigned* tokS   = (unsigned*)bufB + (size_t)NBG*CAPG;     // 12.8 MB, dead after k_fill4
    unsigned short* aggB = (unsigned short*)bufB;              // bf16 agg output

    hipMemsetAsync(gcD, 0, (size_t)NBG*4, stream);
    hipMemsetAsync(gcS, 0, (size_t)NBG*4, stream);
    hipMemsetAsync(stats, 0, 3*512*4, stream);

    const int GB = (NN + 63)/64;   // 1563 GEMM blocks

    // ---- build ----
    k_prepw<<<176, 256, 0, stream>>>(w0, w1, w2, wfc, wt);
    k_bucket2<<<NBLK, 512, 0, stream>>>(src, dst, gcD, gcS, pairsD, tokS);
    k_fill4<<<NBK, 256, 0, stream>>>(gcD, gcS, pairsD, tokS, csr, offsets, degi, dego);
    k_node<<<(NN + 255)/256, 256, 0, stream>>>(h, dego, degi, nsrc, ndst, out_w, xn0);

    // ---- layer 0 ----
    k_agg0<<<NN/2, 64, 0, stream>>>(xn0, offsets, degi, csr, aggB);
    k_gemm_mfma<32,128,true,true,false><<<GB, 256, 0, stream>>>(aggB, wt, b0, ndst, bufA, stats + 0*512);
    k_bnfin<<<1, 128, 0, stream>>>(stats + 0*512, g0, bt0);
    k_bnapply_bf<<<(NN*64 + 255)/256, 256, 0, stream>>>((unsigned*)bufA, stats + 0*512, nsrc, bufC);

    // ---- layer 1 ----
    k_agg_bf<<<NN, 64, 0, stream>>>(bufC, offsets, degi, csr, (unsigned*)aggB);
    k_gemm_mfma<128,128,true,true,false><<<GB, 256, 0, stream>>>(aggB, wt + 4096, b1, ndst, bufA, stats + 1*512);
    k_bnfin<<<1, 128, 0, stream>>>(stats + 1*512, g1, bt1);
    k_bnapply_bf<<<(NN*64 + 255)/256, 256, 0, stream>>>((unsigned*)bufA, stats + 1*512, nsrc, bufC);

    // ---- layer 2 ----
    k_agg_bf<<<NN, 64, 0, stream>>>(bufC, offsets, degi, csr, (unsigned*)aggB);
    k_gemm_mfma<128,128,true,true,false><<<GB, 256, 0, stream>>>(aggB, wt + 20480, b2, ndst, bufA, stats + 2*512);
    k_bnfin<<<1, 128, 0, stream>>>(stats + 2*512, g2, bt2);
    k_bnapply_bf<<<(NN*64 + 255)/256, 256, 0, stream>>>((unsigned*)bufA, stats + 2*512, nullptr, bufC);

    // ---- FC: out = x @ wfc + bfc ----
    k_gemm_mfma<128,64,false,false,true><<<GB, 256, 0, stream>>>((unsigned short*)bufC, wt + 36864, bfc,
                                                                 nullptr, out, nullptr);
}

// Round 9
// 477.500 us; speedup vs baseline: 6.5686x; 1.1128x over previous
//
#include <hip/hip_runtime.h>

#define NN 100000
#define NE 1600000
#define BN_EPS 1e-5f
#define CSHIFT 9
#define NBC ((NN + 511) >> CSHIFT)   // 196 coarse buckets of 512 nodes
#define CAPC 10240                   // slots per coarse bucket (mean 8163)
#define EPB1 4096
#define NBLK1 ((NE + EPB1 - 1)/EPB1) // 391 pass-1 blocks

typedef short bf16x8 __attribute__((ext_vector_type(8)));
typedef float f32x4  __attribute__((ext_vector_type(4)));

__constant__ float c_wtab[26] = {0.7f,0.9f,0.7f,0.9f,0.3f,0.7f,0.3f,0.9f,0.3f,0.3f,0.9f,0.7f,0.1f,
                                 0.9f,0.5f,0.9f,0.5f,0.5f,0.1f,0.3f,0.7f,0.9f,0.9f,0.9f,0.9f,0.9f};

__device__ __forceinline__ unsigned f2bf(float f){
    unsigned u = __float_as_uint(f);
    return (u + 0x7fffu + ((u >> 16) & 1u)) >> 16;   // round-to-nearest-even
}
__device__ __forceinline__ float bflo(unsigned v){ return __uint_as_float(v << 16); }
__device__ __forceinline__ float bfhi(unsigned v){ return __uint_as_float(v & 0xffff0000u); }

// ---- weight prep: transpose + bf16 (Bt[col][k] layout for MFMA B-operand) ----
__global__ void k_prepw(const float* __restrict__ w0, const float* __restrict__ w1,
                        const float* __restrict__ w2, const float* __restrict__ wfc,
                        unsigned short* __restrict__ wt){
    int i = blockIdx.x*256 + threadIdx.x;
    if (i < 4096){                       // w0t: [128 cols][32 k], k>=26 zero
        int c = i >> 5, k = i & 31;
        float v = (k < 26) ? w0[k*128 + c] : 0.f;
        wt[i] = (unsigned short)f2bf(v);
    } else if (i < 20480){               // w1t: [128][128]
        int j = i - 4096; int c = j >> 7, k = j & 127;
        wt[i] = (unsigned short)f2bf(w1[k*128 + c]);
    } else if (i < 36864){               // w2t: [128][128]
        int j = i - 20480; int c = j >> 7, k = j & 127;
        wt[i] = (unsigned short)f2bf(w2[k*128 + c]);
    } else if (i < 45056){               // wfct: [64][128]
        int j = i - 36864; int c = j >> 7, k = j & 127;
        wt[i] = (unsigned short)f2bf(wfc[k*64 + c]);
    }
}

// ---- cursor init: per-coarse-bucket region bases ----
__global__ void k_init(unsigned* __restrict__ gcurD, unsigned* __restrict__ gcurS){
    int i = blockIdx.x*256 + threadIdx.x;
    if (i < NBC){ gcurD[i] = (unsigned)i*CAPC; gcurS[i] = (unsigned)i*CAPC; }
}

// ---- pass 1: coarse radix scatter, run-reserved contiguous writes ----
__global__ __launch_bounds__(512) void k_radix1(const int* __restrict__ src,
                                                const int* __restrict__ dst,
                                                unsigned* __restrict__ gcurD,
                                                unsigned* __restrict__ gcurS,
                                                unsigned* __restrict__ pairs,
                                                unsigned short* __restrict__ tok){
    __shared__ unsigned hD[NBC], hS[NBC];
    int tid = threadIdx.x;
    for (int i = tid; i < NBC; i += 512){ hD[i] = 0u; hS[i] = 0u; }
    __syncthreads();
    int base = blockIdx.x*EPB1;
    int n = NE - base; if (n > EPB1) n = EPB1;
    for (int k = tid; k < n; k += 512){
        atomicAdd(&hD[(unsigned)dst[base+k] >> CSHIFT], 1u);
        atomicAdd(&hS[(unsigned)src[base+k] >> CSHIFT], 1u);
    }
    __syncthreads();
    // reserve one contiguous run per touched bucket; hD/hS become cursors
    for (int i = tid; i < NBC; i += 512){
        unsigned c = hD[i];
        hD[i] = c ? atomicAdd(&gcurD[i], c) : 0u;
        c = hS[i];
        hS[i] = c ? atomicAdd(&gcurS[i], c) : 0u;
    }
    __syncthreads();
    for (int k = tid; k < n; k += 512){
        int d = dst[base+k], s = src[base+k];
        unsigned bb = (unsigned)d >> CSHIFT;
        unsigned p = atomicAdd(&hD[bb], 1u);
        if (p < (bb+1)*CAPC)
            pairs[p] = ((unsigned)(d & 511) << 17) | (unsigned)s;
        bb = (unsigned)s >> CSHIFT;
        p = atomicAdd(&hS[bb], 1u);
        if (p < (bb+1)*CAPC)
            tok[p] = (unsigned short)(s & 511);
    }
}

// ---- pass 2: block-per-coarse-bucket -> exact CSR + degi + dego (no global atomics) ----
__global__ __launch_bounds__(1024) void k_radix2(const unsigned* __restrict__ gcurD,
                                                 const unsigned* __restrict__ gcurS,
                                                 const unsigned* __restrict__ pairs,
                                                 const unsigned short* __restrict__ tok,
                                                 int* __restrict__ csr,
                                                 unsigned* __restrict__ offs,
                                                 unsigned* __restrict__ degi,
                                                 unsigned* __restrict__ dego){
    __shared__ unsigned cnt[512], cur[512], scnt[512];
    int b = blockIdx.x, tid = threadIdx.x;
    if (tid < 512){ cnt[tid] = 0u; scnt[tid] = 0u; }
    __syncthreads();
    unsigned baseC = (unsigned)b*CAPC;
    unsigned nD = gcurD[b] - baseC; if (nD > CAPC) nD = CAPC;
    unsigned nS = gcurS[b] - baseC; if (nS > CAPC) nS = CAPC;
    for (unsigned i = tid; i < nD; i += 1024)
        atomicAdd(&cnt[pairs[baseC + i] >> 17], 1u);
    for (unsigned i = tid; i < nS; i += 1024)
        atomicAdd(&scnt[tok[baseC + i]], 1u);
    __syncthreads();
    if (tid < 512) cur[tid] = cnt[tid];
    __syncthreads();
    for (int o = 1; o < 512; o <<= 1){
        unsigned x = 0;
        if (tid < 512 && tid >= o) x = cur[tid - o];
        __syncthreads();
        if (tid < 512) cur[tid] += x;
        __syncthreads();
    }
    if (tid < 512){
        unsigned ex = cur[tid] - cnt[tid];   // exclusive prefix
        int node = (b << CSHIFT) + tid;
        if (node < NN){
            offs[node] = baseC + ex;
            degi[node] = cnt[tid];
            dego[node] = scnt[tid];
        }
        cur[tid] = ex;                       // becomes placement cursor
    }
    __syncthreads();
    for (unsigned i = tid; i < nD; i += 1024){
        unsigned pr = pairs[baseC + i];
        unsigned p = atomicAdd(&cur[pr >> 17], 1u);
        csr[baseC + p] = (int)(pr & 0x1FFFFu);
    }
}

// ---------------- per-node: norms + argmax weight + xn0 = h*nsrc (padded [N,32]) ----------------
__global__ void k_node(const float* __restrict__ h, const unsigned* __restrict__ dego,
                       const unsigned* __restrict__ degi, float* __restrict__ nsrc,
                       float* __restrict__ ndst, float* __restrict__ outw,
                       float* __restrict__ xn0){
    int i = blockIdx.x*blockDim.x + threadIdx.x;
    if (i < NN){
        float d0 = (float)dego[i]; d0 = d0 < 1.f ? 1.f : d0;
        float d1 = (float)degi[i]; d1 = d1 < 1.f ? 1.f : d1;
        float ns = rsqrtf(d0);
        nsrc[i] = ns;
        ndst[i] = rsqrtf(d1);
        float row[26];
        #pragma unroll
        for (int c = 0; c < 26; ++c) row[c] = h[(size_t)i*26 + c];
        float best = row[0]; int bi = 0;
        #pragma unroll
        for (int c = 1; c < 26; ++c){ if (row[c] > best){ best = row[c]; bi = c; } }
        outw[i] = c_wtab[bi];
        #pragma unroll
        for (int c = 0; c < 26; ++c) xn0[(size_t)i*32 + c] = row[c]*ns;
        #pragma unroll
        for (int c = 26; c < 32; ++c) xn0[(size_t)i*32 + c] = 0.f;
    }
}

// ---------------- layer-0 aggregation -> bf16 [N,32] ----------------
__global__ __launch_bounds__(64) void k_agg0(const float* __restrict__ xn,
                                             const unsigned* __restrict__ offs,
                                             const unsigned* __restrict__ degi,
                                             const int* __restrict__ csr,
                                             unsigned short* __restrict__ agg){
    int node = blockIdx.x*2 + (threadIdx.x >> 5);
    int c = threadIdx.x & 31;
    unsigned beg = offs[node], end = beg + degi[node];
    float acc = 0.f;
    unsigned e = beg;
    for (; e + 4 <= end; e += 4){
        int s0 = csr[e+0], s1 = csr[e+1], s2 = csr[e+2], s3 = csr[e+3];
        float a0 = xn[(size_t)s0*32 + c];
        float a1 = xn[(size_t)s1*32 + c];
        float a2 = xn[(size_t)s2*32 + c];
        float a3 = xn[(size_t)s3*32 + c];
        acc += (a0 + a1) + (a2 + a3);
    }
    for (; e < end; ++e)
        acc += xn[(size_t)csr[e]*32 + c];
    agg[(size_t)node*32 + c] = (unsigned short)f2bf(acc);
}

// ---------------- layers 1/2 aggregation: bf16 gather -> bf16 [N,128] ----------------
__global__ __launch_bounds__(64) void k_agg_bf(const unsigned* __restrict__ xn,
                                               const unsigned* __restrict__ offs,
                                               const unsigned* __restrict__ degi,
                                               const int* __restrict__ csr,
                                               unsigned* __restrict__ agg){
    int node = blockIdx.x;
    int t = threadIdx.x;   // dword t = channels (2t, 2t+1)
    unsigned beg = offs[node], end = beg + degi[node];
    float a0 = 0.f, a1 = 0.f;
    unsigned e = beg;
    for (; e + 8 <= end; e += 8){
        int s[8];
        #pragma unroll
        for (int i = 0; i < 8; ++i) s[i] = csr[e + i];
        #pragma unroll
        for (int i = 0; i < 8; ++i){
            unsigned v = xn[(size_t)s[i]*64 + t];
            a0 += bflo(v);
            a1 += bfhi(v);
        }
    }
    for (; e < end; ++e){
        unsigned v = xn[(size_t)csr[e]*64 + t];
        a0 += bflo(v);
        a1 += bfhi(v);
    }
    agg[(size_t)node*64 + t] = f2bf(a0) | (f2bf(a1) << 16);
}

// ---------------- MFMA GEMM: Z = A(bf16) @ Bt^T (*ndst) + bias, fused BN stats ----------------
// A: [NN][CIN] bf16 row-major; Bt: [COUT][CIN] bf16. Z: bf16 (pre-BN) or fp32 (FC).
template<int CIN, int COUT, bool STATS, bool NDST, bool F32OUT>
__global__ __launch_bounds__(256) void k_gemm_mfma(const unsigned short* __restrict__ A,
                                                   const unsigned short* __restrict__ Bt,
                                                   const float* __restrict__ bias,
                                                   const float* __restrict__ ndst,
                                                   void* __restrict__ Zv,
                                                   float* __restrict__ stats){
    constexpr int KD = CIN/2;     // dwords per row
    constexpr int NT = COUT/16;   // 16-col tiles per wave
    __shared__ char sA[64*CIN*2];
    __shared__ char sB[COUT*CIN*2];
    __shared__ float sS[2][COUT];
    float* Zf = (float*)Zv;
    unsigned short* Zh = (unsigned short*)Zv;
    const int tid = threadIdx.x;
    const int row0 = blockIdx.x*64;
    // stage A (bf16, XOR-swizzled rows)
    const unsigned* Ad = (const unsigned*)A;
    for (int i = tid; i < 64*KD; i += 256){
        int r = i/KD, c2 = i - r*KD;
        int gr = row0 + r;
        unsigned v = (gr < NN) ? Ad[(size_t)gr*KD + c2] : 0u;
        *(unsigned*)(sA + ((r*CIN*2 + c2*4) ^ ((r&7)<<4))) = v;
    }
    // stage Bt (bf16, same swizzle keyed on col)
    const unsigned* Bd = (const unsigned*)Bt;
    for (int i = tid; i < COUT*KD; i += 256){
        int cc = i/KD, c2 = i - cc*KD;
        *(unsigned*)(sB + ((cc*CIN*2 + c2*4) ^ ((cc&7)<<4))) = Bd[i];
    }
    if (STATS){
        for (int i = tid; i < 2*COUT; i += 256) (&sS[0][0])[i] = 0.f;
    }
    __syncthreads();
    const int w = tid >> 6, lane = tid & 63;
    const int lrow = lane & 15, kg = lane >> 4;
    f32x4 acc[NT];
    #pragma unroll
    for (int n = 0; n < NT; ++n) acc[n] = (f32x4){0.f,0.f,0.f,0.f};
    const int arow = w*16 + lrow;
    #pragma unroll
    for (int kk = 0; kk < CIN/32; ++kk){
        const int kb = kk*64 + kg*16;
        bf16x8 af = *(const bf16x8*)(sA + ((arow*CIN*2 + kb) ^ ((arow&7)<<4)));
        #pragma unroll
        for (int n = 0; n < NT; ++n){
            int bc = n*16 + lrow;
            bf16x8 bv = *(const bf16x8*)(sB + ((bc*CIN*2 + kb) ^ ((bc&7)<<4)));
            acc[n] = __builtin_amdgcn_mfma_f32_16x16x32_bf16(af, bv, acc[n], 0, 0, 0);
        }
    }
    // epilogue: C/D mapping col=lane&15, row=(lane>>4)*4+j  [m89-verified]
    int grow[4]; float nm[4]; bool val[4];
    #pragma unroll
    for (int j = 0; j < 4; ++j){
        grow[j] = row0 + w*16 + kg*4 + j;
        val[j]  = grow[j] < NN;
        nm[j]   = (NDST && val[j]) ? ndst[grow[j]] : 1.f;
    }
    #pragma unroll
    for (int n = 0; n < NT; ++n){
        int gcol = n*16 + lrow;
        float bv = bias[gcol];
        float cs = 0.f, cq = 0.f;
        #pragma unroll
        for (int j = 0; j < 4; ++j){
            float z = acc[n][j]*nm[j] + bv;
            if (val[j]){
                if (F32OUT) Zf[(size_t)grow[j]*COUT + gcol] = z;
                else        Zh[(size_t)grow[j]*COUT + gcol] = (unsigned short)f2bf(z);
                if (STATS){ cs += z; cq += z*z; }
            }
        }
        if (STATS){
            cs += __shfl_xor(cs, 16); cs += __shfl_xor(cs, 32);
            cq += __shfl_xor(cq, 16); cq += __shfl_xor(cq, 32);
            if (kg == 0){
                atomicAdd(&sS[0][gcol], cs);
                atomicAdd(&sS[1][gcol], cq);
            }
        }
    }
    if (STATS){
        __syncthreads();
        for (int i = tid; i < COUT; i += 256){
            atomicAdd(&stats[i],       sS[0][i]);
            atomicAdd(&stats[128 + i], sS[1][i]);
        }
    }
}

// ---------------- BN finalize: scale/shift ----------------
__global__ void k_bnfin(float* __restrict__ stats, const float* __restrict__ g,
                        const float* __restrict__ bt){
    int c = threadIdx.x;  // 128
    float mu  = stats[c] / (float)NN;
    float var = stats[128 + c] / (float)NN - mu*mu;
    if (var < 0.f) var = 0.f;
    float sc = g[c] * rsqrtf(var + BN_EPS);
    stats[256 + c] = sc;
    stats[384 + c] = bt[c] - mu*sc;
}

// ---------------- BN apply + ReLU (+ optional *nsrc): bf16 Z -> bf16 features ----------------
__global__ void k_bnapply_bf(const unsigned* __restrict__ Xb, const float* __restrict__ stats,
                             const float* __restrict__ nsrc, unsigned* __restrict__ out){
    int idx = blockIdx.x*blockDim.x + threadIdx.x;
    if (idx < NN*64){
        int d = idx & 63;
        int node = idx >> 6;
        int c0 = d << 1;
        unsigned v = Xb[idx];            // bf16 pair: cols (2d, 2d+1)
        float v0 = bflo(v)*stats[256 + c0]     + stats[384 + c0];
        float v1 = bfhi(v)*stats[256 + c0 + 1] + stats[384 + c0 + 1];
        float ns = nsrc ? nsrc[node] : 1.f;
        v0 = v0 > 0.f ? v0*ns : 0.f;
        v1 = v1 > 0.f ? v1*ns : 0.f;
        out[idx] = f2bf(v0) | (f2bf(v1) << 16);
    }
}

extern "C" void kernel_launch(void* const* d_in, const int* in_sizes, int n_in,
                              void* d_out, int out_size, void* d_ws, size_t ws_size,
                              hipStream_t stream) {
    const float* h   = (const float*)d_in[0];
    const int*   src = (const int*)d_in[1];
    const int*   dst = (const int*)d_in[2];
    const float* w0  = (const float*)d_in[3];
    const float* b0  = (const float*)d_in[4];
    const float* w1  = (const float*)d_in[5];
    const float* b1  = (const float*)d_in[6];
    const float* w2  = (const float*)d_in[7];
    const float* b2  = (const float*)d_in[8];
    const float* g0  = (const float*)d_in[9];
    const float* bt0 = (const float*)d_in[10];
    const float* g1  = (const float*)d_in[11];
    const float* bt1 = (const float*)d_in[12];
    const float* g2  = (const float*)d_in[13];
    const float* bt2 = (const float*)d_in[14];
    const float* wfc = (const float*)d_in[15];
    const float* bfc = (const float*)d_in[16];

    float* out   = (float*)d_out;                     // [NN,64]
    float* out_w = out + (size_t)NN*64;               // [NN,1]

    char* ws = (char*)d_ws;
    size_t off = 0;
    auto alloc = [&](size_t b){ size_t p = off; off += (b + 255) & ~(size_t)255; return ws + p; };

    unsigned*       dego    = (unsigned*)alloc((size_t)NN*4);
    unsigned*       degi    = (unsigned*)alloc((size_t)NN*4);
    float*          nsrc    = (float*)   alloc((size_t)NN*4);
    float*          ndst    = (float*)   alloc((size_t)NN*4);
    unsigned*       offsets = (unsigned*)alloc((size_t)NN*4);
    unsigned*       gcurD   = (unsigned*)alloc((size_t)NBC*4);
    unsigned*       gcurS   = (unsigned*)alloc((size_t)NBC*4);
    float*          stats   = (float*)   alloc(3*512*4);
    unsigned short* wt      = (unsigned short*)alloc(45056*2);  // bf16 transposed weights
    int*            csr     = (int*)     alloc((size_t)NBC*CAPC*4);   // 8 MB exact CSR
    float*          xn0     = (float*)   alloc((size_t)NN*32*4);
    unsigned short* bufA    = (unsigned short*)alloc((size_t)NN*128*2); // GEMM out (bf16 pre-BN)
    float*          bufB    = (float*)   alloc((size_t)NN*128*4);   // agg out / radix scratch alias
    unsigned*       bufC    = (unsigned*)alloc((size_t)NN*64*4);    // bf16 features
    (void)ws_size; (void)in_sizes; (void)n_in; (void)out_size;

    unsigned*       pairs = (unsigned*)bufB;                          // 8 MB
    unsigned short* tok   = (unsigned short*)((char*)bufB + (size_t)NBC*CAPC*4); // 4 MB
    unsigned short* aggB  = (unsigned short*)bufB;                    // bf16 agg output (after radix)

    hipMemsetAsync(stats, 0, 3*512*4, stream);

    const int GB = (NN + 63)/64;   // 1563 GEMM blocks

    // ---- build: weight prep + 2-pass coarse radix -> exact CSR + degrees ----
    k_prepw<<<176, 256, 0, stream>>>(w0, w1, w2, wfc, wt);
    k_init<<<1, 256, 0, stream>>>(gcurD, gcurS);
    k_radix1<<<NBLK1, 512, 0, stream>>>(src, dst, gcurD, gcurS, pairs, tok);
    k_radix2<<<NBC, 1024, 0, stream>>>(gcurD, gcurS, pairs, tok, csr, offsets, degi, dego);
    k_node<<<(NN + 255)/256, 256, 0, stream>>>(h, dego, degi, nsrc, ndst, out_w, xn0);

    // ---- layer 0 ----
    k_agg0<<<NN/2, 64, 0, stream>>>(xn0, offsets, degi, csr, aggB);
    k_gemm_mfma<32,128,true,true,false><<<GB, 256, 0, stream>>>(aggB, wt, b0, ndst, bufA, stats + 0*512);
    k_bnfin<<<1, 128, 0, stream>>>(stats + 0*512, g0, bt0);
    k_bnapply_bf<<<(NN*64 + 255)/256, 256, 0, stream>>>((unsigned*)bufA, stats + 0*512, nsrc, bufC);

    // ---- layer 1 ----
    k_agg_bf<<<NN, 64, 0, stream>>>(bufC, offsets, degi, csr, (unsigned*)aggB);
    k_gemm_mfma<128,128,true,true,false><<<GB, 256, 0, stream>>>(aggB, wt + 4096, b1, ndst, bufA, stats + 1*512);
    k_bnfin<<<1, 128, 0, stream>>>(stats + 1*512, g1, bt1);
    k_bnapply_bf<<<(NN*64 + 255)/256, 256, 0, stream>>>((unsigned*)bufA, stats + 1*512, nsrc, bufC);

    // ---- layer 2 ----
    k_agg_bf<<<NN, 64, 0, stream>>>(bufC, offsets, degi, csr, (unsigned*)aggB);
    k_gemm_mfma<128,128,true,true,false><<<GB, 256, 0, stream>>>(aggB, wt + 20480, b2, ndst, bufA, stats + 2*512);
    k_bnfin<<<1, 128, 0, stream>>>(stats + 2*512, g2, bt2);
    k_bnapply_bf<<<(NN*64 + 255)/256, 256, 0, stream>>>((unsigned*)bufA, stats + 2*512, nullptr, bufC);

    // ---- FC: out = x @ wfc + bfc ----
    k_gemm_mfma<128,64,false,false,true><<<GB, 256, 0, stream>>>((unsigned short*)bufC, wt + 36864, bfc,
                                                                 nullptr, out, nullptr);
}

// Round 10
// 374.249 us; speedup vs baseline: 8.3808x; 1.2759x over previous
//
#include <hip/hip_runtime.h>

#define NN 100000
#define NE 1600000
#define BN_EPS 1e-5f
#define CSHIFT 9
#define NBC ((NN + 511) >> CSHIFT)   // 196 coarse buckets of 512 nodes
#define CAPC 10240                   // slots per coarse bucket (mean 8163)
#define EPB1 4096
#define NBLK1 ((NE + EPB1 - 1)/EPB1) // 391 pass-1 blocks
#define NTILES ((NN + 63)/64)        // 1563 row tiles
#define GGRID 521                    // 521*3 = 1563 exactly
#define NPAGE 64                     // stats partial pages

typedef short bf16x8 __attribute__((ext_vector_type(8)));
typedef float f32x4  __attribute__((ext_vector_type(4)));

__constant__ float c_wtab[26] = {0.7f,0.9f,0.7f,0.9f,0.3f,0.7f,0.3f,0.9f,0.3f,0.3f,0.9f,0.7f,0.1f,
                                 0.9f,0.5f,0.9f,0.5f,0.5f,0.1f,0.3f,0.7f,0.9f,0.9f,0.9f,0.9f,0.9f};

__device__ __forceinline__ unsigned f2bf(float f){
    unsigned u = __float_as_uint(f);
    return (u + 0x7fffu + ((u >> 16) & 1u)) >> 16;   // round-to-nearest-even
}
__device__ __forceinline__ float bflo(unsigned v){ return __uint_as_float(v << 16); }
__device__ __forceinline__ float bfhi(unsigned v){ return __uint_as_float(v & 0xffff0000u); }

// ---- weight prep: transpose + bf16 (Bt[col][k] layout for MFMA B-operand) ----
__global__ void k_prepw(const float* __restrict__ w0, const float* __restrict__ w1,
                        const float* __restrict__ w2, const float* __restrict__ wfc,
                        unsigned short* __restrict__ wt){
    int i = blockIdx.x*256 + threadIdx.x;
    if (i < 4096){                       // w0t: [128 cols][32 k], k>=26 zero
        int c = i >> 5, k = i & 31;
        float v = (k < 26) ? w0[k*128 + c] : 0.f;
        wt[i] = (unsigned short)f2bf(v);
    } else if (i < 20480){               // w1t: [128][128]
        int j = i - 4096; int c = j >> 7, k = j & 127;
        wt[i] = (unsigned short)f2bf(w1[k*128 + c]);
    } else if (i < 36864){               // w2t: [128][128]
        int j = i - 20480; int c = j >> 7, k = j & 127;
        wt[i] = (unsigned short)f2bf(w2[k*128 + c]);
    } else if (i < 45056){               // wfct: [64][128]
        int j = i - 36864; int c = j >> 7, k = j & 127;
        wt[i] = (unsigned short)f2bf(wfc[k*64 + c]);
    }
}

// ---- cursor init: per-coarse-bucket region bases ----
__global__ void k_init(unsigned* __restrict__ gcurD, unsigned* __restrict__ gcurS){
    int i = blockIdx.x*256 + threadIdx.x;
    if (i < NBC){ gcurD[i] = (unsigned)i*CAPC; gcurS[i] = (unsigned)i*CAPC; }
}

// ---- pass 1: coarse radix scatter, run-reserved contiguous writes ----
__global__ __launch_bounds__(512) void k_radix1(const int* __restrict__ src,
                                                const int* __restrict__ dst,
                                                unsigned* __restrict__ gcurD,
                                                unsigned* __restrict__ gcurS,
                                                unsigned* __restrict__ pairs,
                                                unsigned short* __restrict__ tok){
    __shared__ unsigned hD[NBC], hS[NBC];
    int tid = threadIdx.x;
    for (int i = tid; i < NBC; i += 512){ hD[i] = 0u; hS[i] = 0u; }
    __syncthreads();
    int base = blockIdx.x*EPB1;
    int n = NE - base; if (n > EPB1) n = EPB1;
    for (int k = tid; k < n; k += 512){
        atomicAdd(&hD[(unsigned)dst[base+k] >> CSHIFT], 1u);
        atomicAdd(&hS[(unsigned)src[base+k] >> CSHIFT], 1u);
    }
    __syncthreads();
    for (int i = tid; i < NBC; i += 512){
        unsigned c = hD[i];
        hD[i] = c ? atomicAdd(&gcurD[i], c) : 0u;
        c = hS[i];
        hS[i] = c ? atomicAdd(&gcurS[i], c) : 0u;
    }
    __syncthreads();
    for (int k = tid; k < n; k += 512){
        int d = dst[base+k], s = src[base+k];
        unsigned bb = (unsigned)d >> CSHIFT;
        unsigned p = atomicAdd(&hD[bb], 1u);
        if (p < (bb+1)*CAPC)
            pairs[p] = ((unsigned)(d & 511) << 17) | (unsigned)s;
        bb = (unsigned)s >> CSHIFT;
        p = atomicAdd(&hS[bb], 1u);
        if (p < (bb+1)*CAPC)
            tok[p] = (unsigned short)(s & 511);
    }
}

// ---- pass 2: block-per-coarse-bucket -> exact CSR + degi + dego (no global atomics) ----
__global__ __launch_bounds__(1024) void k_radix2(const unsigned* __restrict__ gcurD,
                                                 const unsigned* __restrict__ gcurS,
                                                 const unsigned* __restrict__ pairs,
                                                 const unsigned short* __restrict__ tok,
                                                 int* __restrict__ csr,
                                                 unsigned* __restrict__ offs,
                                                 unsigned* __restrict__ degi,
                                                 unsigned* __restrict__ dego){
    __shared__ unsigned cnt[512], cur[512], scnt[512];
    int b = blockIdx.x, tid = threadIdx.x;
    if (tid < 512){ cnt[tid] = 0u; scnt[tid] = 0u; }
    __syncthreads();
    unsigned baseC = (unsigned)b*CAPC;
    unsigned nD = gcurD[b] - baseC; if (nD > CAPC) nD = CAPC;
    unsigned nS = gcurS[b] - baseC; if (nS > CAPC) nS = CAPC;
    for (unsigned i = tid; i < nD; i += 1024)
        atomicAdd(&cnt[pairs[baseC + i] >> 17], 1u);
    for (unsigned i = tid; i < nS; i += 1024)
        atomicAdd(&scnt[tok[baseC + i]], 1u);
    __syncthreads();
    if (tid < 512) cur[tid] = cnt[tid];
    __syncthreads();
    for (int o = 1; o < 512; o <<= 1){
        unsigned x = 0;
        if (tid < 512 && tid >= o) x = cur[tid - o];
        __syncthreads();
        if (tid < 512) cur[tid] += x;
        __syncthreads();
    }
    if (tid < 512){
        unsigned ex = cur[tid] - cnt[tid];   // exclusive prefix
        int node = (b << CSHIFT) + tid;
        if (node < NN){
            offs[node] = baseC + ex;
            degi[node] = cnt[tid];
            dego[node] = scnt[tid];
        }
        cur[tid] = ex;                       // becomes placement cursor
    }
    __syncthreads();
    for (unsigned i = tid; i < nD; i += 1024){
        unsigned pr = pairs[baseC + i];
        unsigned p = atomicAdd(&cur[pr >> 17], 1u);
        csr[baseC + p] = (int)(pr & 0x1FFFFu);
    }
}

// ---------------- per-node: norms + argmax weight + xn0 = h*nsrc (padded [N,32]) ----------------
__global__ void k_node(const float* __restrict__ h, const unsigned* __restrict__ dego,
                       const unsigned* __restrict__ degi, float* __restrict__ nsrc,
                       float* __restrict__ ndst, float* __restrict__ outw,
                       float* __restrict__ xn0){
    int i = blockIdx.x*blockDim.x + threadIdx.x;
    if (i < NN){
        float d0 = (float)dego[i]; d0 = d0 < 1.f ? 1.f : d0;
        float d1 = (float)degi[i]; d1 = d1 < 1.f ? 1.f : d1;
        float ns = rsqrtf(d0);
        nsrc[i] = ns;
        ndst[i] = rsqrtf(d1);
        float row[26];
        #pragma unroll
        for (int c = 0; c < 26; ++c) row[c] = h[(size_t)i*26 + c];
        float best = row[0]; int bi = 0;
        #pragma unroll
        for (int c = 1; c < 26; ++c){ if (row[c] > best){ best = row[c]; bi = c; } }
        outw[i] = c_wtab[bi];
        #pragma unroll
        for (int c = 0; c < 26; ++c) xn0[(size_t)i*32 + c] = row[c]*ns;
        #pragma unroll
        for (int c = 26; c < 32; ++c) xn0[(size_t)i*32 + c] = 0.f;
    }
}

// ---------------- layer-0 aggregation -> bf16 [N,32] ----------------
__global__ __launch_bounds__(64) void k_agg0(const float* __restrict__ xn,
                                             const unsigned* __restrict__ offs,
                                             const unsigned* __restrict__ degi,
                                             const int* __restrict__ csr,
                                             unsigned short* __restrict__ agg){
    int node = blockIdx.x*2 + (threadIdx.x >> 5);
    int c = threadIdx.x & 31;
    unsigned beg = offs[node], end = beg + degi[node];
    float acc = 0.f;
    unsigned e = beg;
    for (; e + 4 <= end; e += 4){
        int s0 = csr[e+0], s1 = csr[e+1], s2 = csr[e+2], s3 = csr[e+3];
        float a0 = xn[(size_t)s0*32 + c];
        float a1 = xn[(size_t)s1*32 + c];
        float a2 = xn[(size_t)s2*32 + c];
        float a3 = xn[(size_t)s3*32 + c];
        acc += (a0 + a1) + (a2 + a3);
    }
    for (; e < end; ++e)
        acc += xn[(size_t)csr[e]*32 + c];
    agg[(size_t)node*32 + c] = (unsigned short)f2bf(acc);
}

// ---------------- layers 1/2 aggregation: bf16 gather -> bf16 [N,128] ----------------
__global__ __launch_bounds__(64) void k_agg_bf(const unsigned* __restrict__ xn,
                                               const unsigned* __restrict__ offs,
                                               const unsigned* __restrict__ degi,
                                               const int* __restrict__ csr,
                                               unsigned* __restrict__ agg){
    int node = blockIdx.x;
    int t = threadIdx.x;   // dword t = channels (2t, 2t+1)
    unsigned beg = offs[node], end = beg + degi[node];
    float a0 = 0.f, a1 = 0.f;
    unsigned e = beg;
    for (; e + 8 <= end; e += 8){
        int s[8];
        #pragma unroll
        for (int i = 0; i < 8; ++i) s[i] = csr[e + i];
        #pragma unroll
        for (int i = 0; i < 8; ++i){
            unsigned v = xn[(size_t)s[i]*64 + t];
            a0 += bflo(v);
            a1 += bfhi(v);
        }
    }
    for (; e < end; ++e){
        unsigned v = xn[(size_t)csr[e]*64 + t];
        a0 += bflo(v);
        a1 += bfhi(v);
    }
    agg[(size_t)node*64 + t] = f2bf(a0) | (f2bf(a1) << 16);
}

// ---------------- MFMA GEMM (grid-strided): Z = A(bf16) @ Bt^T (*ndst) + bias ----------------
// B staged once per block; stats carried in registers, flushed once to spread pages.
template<int CIN, int COUT, bool STATS, bool NDST, bool F32OUT>
__global__ __launch_bounds__(256) void k_gemm_mfma(const unsigned short* __restrict__ A,
                                                   const unsigned short* __restrict__ Bt,
                                                   const float* __restrict__ bias,
                                                   const float* __restrict__ ndst,
                                                   void* __restrict__ Zv,
                                                   float* __restrict__ part){
    constexpr int KD4 = CIN/8;    // uint4 per row
    constexpr int NT = COUT/16;   // 16-col tiles per wave
    __shared__ char sA[64*CIN*2];
    __shared__ char sB[COUT*CIN*2];
    __shared__ float sS[2][COUT];
    float* Zf = (float*)Zv;
    unsigned short* Zh = (unsigned short*)Zv;
    const int tid = threadIdx.x;
    const int w = tid >> 6, lane = tid & 63;
    const int lrow = lane & 15, kg = lane >> 4;

    // stage Bt once (uint4, XOR-swizzled by col)
    const uint4* B4 = (const uint4*)Bt;
    for (int i = tid; i < COUT*KD4; i += 256){
        int cc = i/KD4, c4 = i - cc*KD4;
        *(uint4*)(sB + ((cc*CIN*2 + c4*16) ^ ((cc&7)<<4))) = B4[i];
    }
    if (STATS){
        for (int i = tid; i < 2*COUT; i += 256) (&sS[0][0])[i] = 0.f;
    }

    float cs[NT], cq[NT];
    #pragma unroll
    for (int n = 0; n < NT; ++n){ cs[n] = 0.f; cq[n] = 0.f; }

    const uint4* A4 = (const uint4*)A;
    const uint4 z4 = make_uint4(0,0,0,0);
    for (int t = blockIdx.x; t < NTILES; t += GGRID){
        const int row0 = t*64;
        // stage A tile (uint4, swizzled rows)
        for (int i = tid; i < 64*KD4; i += 256){
            int r = i/KD4, c4 = i - r*KD4;
            int gr = row0 + r;
            uint4 v = (gr < NN) ? A4[(size_t)gr*KD4 + c4] : z4;
            *(uint4*)(sA + ((r*CIN*2 + c4*16) ^ ((r&7)<<4))) = v;
        }
        __syncthreads();
        f32x4 acc[NT];
        #pragma unroll
        for (int n = 0; n < NT; ++n) acc[n] = (f32x4){0.f,0.f,0.f,0.f};
        const int arow = w*16 + lrow;
        #pragma unroll
        for (int kk = 0; kk < CIN/32; ++kk){
            const int kb = kk*64 + kg*16;
            bf16x8 af = *(const bf16x8*)(sA + ((arow*CIN*2 + kb) ^ ((arow&7)<<4)));
            #pragma unroll
            for (int n = 0; n < NT; ++n){
                int bc = n*16 + lrow;
                bf16x8 bv = *(const bf16x8*)(sB + ((bc*CIN*2 + kb) ^ ((bc&7)<<4)));
                acc[n] = __builtin_amdgcn_mfma_f32_16x16x32_bf16(af, bv, acc[n], 0, 0, 0);
            }
        }
        // epilogue: C/D mapping col=lane&15, row=(lane>>4)*4+j  [m89-verified]
        int grow[4]; float nm[4]; bool val[4];
        #pragma unroll
        for (int j = 0; j < 4; ++j){
            grow[j] = row0 + w*16 + kg*4 + j;
            val[j]  = grow[j] < NN;
            nm[j]   = (NDST && val[j]) ? ndst[grow[j]] : 1.f;
        }
        #pragma unroll
        for (int n = 0; n < NT; ++n){
            int gcol = n*16 + lrow;
            float bv = bias[gcol];
            #pragma unroll
            for (int j = 0; j < 4; ++j){
                float z = acc[n][j]*nm[j] + bv;
                if (val[j]){
                    if (F32OUT) Zf[(size_t)grow[j]*COUT + gcol] = z;
                    else        Zh[(size_t)grow[j]*COUT + gcol] = (unsigned short)f2bf(z);
                    if (STATS){ cs[n] += z; cq[n] += z*z; }
                }
            }
        }
        __syncthreads();   // protect sA before next tile's restage
    }
    if (STATS){
        #pragma unroll
        for (int n = 0; n < NT; ++n){
            float s = cs[n], q = cq[n];
            s += __shfl_xor(s, 16); s += __shfl_xor(s, 32);
            q += __shfl_xor(q, 16); q += __shfl_xor(q, 32);
            if (kg == 0){
                atomicAdd(&sS[0][n*16 + lrow], s);
                atomicAdd(&sS[1][n*16 + lrow], q);
            }
        }
        __syncthreads();
        float* pg = part + (size_t)(blockIdx.x & (NPAGE-1))*2*COUT;
        for (int i = tid; i < 2*COUT; i += 256)
            atomicAdd(&pg[i], (&sS[0][0])[i]);
    }
}

// ---------------- BN finalize: reduce partial pages -> scale/shift ----------------
__global__ void k_bnfin(const float* __restrict__ part, float* __restrict__ stats,
                        const float* __restrict__ g, const float* __restrict__ bt){
    int c = threadIdx.x;  // 128
    float s = 0.f, q = 0.f;
    #pragma unroll 8
    for (int p = 0; p < NPAGE; ++p){
        s += part[p*256 + c];
        q += part[p*256 + 128 + c];
    }
    float mu  = s / (float)NN;
    float var = q / (float)NN - mu*mu;
    if (var < 0.f) var = 0.f;
    float sc = g[c] * rsqrtf(var + BN_EPS);
    stats[256 + c] = sc;
    stats[384 + c] = bt[c] - mu*sc;
}

// ---------------- BN apply + ReLU (+ optional *nsrc): bf16 Z -> bf16 features ----------------
__global__ void k_bnapply_bf(const unsigned* __restrict__ Xb, const float* __restrict__ stats,
                             const float* __restrict__ nsrc, unsigned* __restrict__ out){
    int idx = blockIdx.x*blockDim.x + threadIdx.x;
    if (idx < NN*64){
        int d = idx & 63;
        int node = idx >> 6;
        int c0 = d << 1;
        unsigned v = Xb[idx];            // bf16 pair: cols (2d, 2d+1)
        float v0 = bflo(v)*stats[256 + c0]     + stats[384 + c0];
        float v1 = bfhi(v)*stats[256 + c0 + 1] + stats[384 + c0 + 1];
        float ns = nsrc ? nsrc[node] : 1.f;
        v0 = v0 > 0.f ? v0*ns : 0.f;
        v1 = v1 > 0.f ? v1*ns : 0.f;
        out[idx] = f2bf(v0) | (f2bf(v1) << 16);
    }
}

extern "C" void kernel_launch(void* const* d_in, const int* in_sizes, int n_in,
                              void* d_out, int out_size, void* d_ws, size_t ws_size,
                              hipStream_t stream) {
    const float* h   = (const float*)d_in[0];
    const int*   src = (const int*)d_in[1];
    const int*   dst = (const int*)d_in[2];
    const float* w0  = (const float*)d_in[3];
    const float* b0  = (const float*)d_in[4];
    const float* w1  = (const float*)d_in[5];
    const float* b1  = (const float*)d_in[6];
    const float* w2  = (const float*)d_in[7];
    const float* b2  = (const float*)d_in[8];
    const float* g0  = (const float*)d_in[9];
    const float* bt0 = (const float*)d_in[10];
    const float* g1  = (const float*)d_in[11];
    const float* bt1 = (const float*)d_in[12];
    const float* g2  = (const float*)d_in[13];
    const float* bt2 = (const float*)d_in[14];
    const float* wfc = (const float*)d_in[15];
    const float* bfc = (const float*)d_in[16];

    float* out   = (float*)d_out;                     // [NN,64]
    float* out_w = out + (size_t)NN*64;               // [NN,1]

    char* ws = (char*)d_ws;
    size_t off = 0;
    auto alloc = [&](size_t b){ size_t p = off; off += (b + 255) & ~(size_t)255; return ws + p; };

    unsigned*       dego    = (unsigned*)alloc((size_t)NN*4);
    unsigned*       degi    = (unsigned*)alloc((size_t)NN*4);
    float*          nsrc    = (float*)   alloc((size_t)NN*4);
    float*          ndst    = (float*)   alloc((size_t)NN*4);
    unsigned*       offsets = (unsigned*)alloc((size_t)NN*4);
    unsigned*       gcurD   = (unsigned*)alloc((size_t)NBC*4);
    unsigned*       gcurS   = (unsigned*)alloc((size_t)NBC*4);
    float*          stats   = (float*)   alloc(3*512*4);            // scale/shift per layer
    float*          spart   = (float*)   alloc(3*(size_t)NPAGE*256*4); // stats partial pages
    unsigned short* wt      = (unsigned short*)alloc(45056*2);  // bf16 transposed weights
    int*            csr     = (int*)     alloc((size_t)NBC*CAPC*4);   // 8 MB exact CSR
    float*          xn0     = (float*)   alloc((size_t)NN*32*4);
    unsigned short* bufA    = (unsigned short*)alloc((size_t)NN*128*2); // GEMM out (bf16 pre-BN)
    float*          bufB    = (float*)   alloc((size_t)NN*128*4);   // agg out / radix scratch alias
    unsigned*       bufC    = (unsigned*)alloc((size_t)NN*64*4);    // bf16 features
    (void)ws_size; (void)in_sizes; (void)n_in; (void)out_size;

    unsigned*       pairs = (unsigned*)bufB;                          // 8 MB
    unsigned short* tok   = (unsigned short*)((char*)bufB + (size_t)NBC*CAPC*4); // 4 MB
    unsigned short* aggB  = (unsigned short*)bufB;                    // bf16 agg output (after radix)

    hipMemsetAsync(spart, 0, 3*(size_t)NPAGE*256*4, stream);

    // ---- build: weight prep + 2-pass coarse radix -> exact CSR + degrees ----
    k_prepw<<<176, 256, 0, stream>>>(w0, w1, w2, wfc, wt);
    k_init<<<1, 256, 0, stream>>>(gcurD, gcurS);
    k_radix1<<<NBLK1, 512, 0, stream>>>(src, dst, gcurD, gcurS, pairs, tok);
    k_radix2<<<NBC, 1024, 0, stream>>>(gcurD, gcurS, pairs, tok, csr, offsets, degi, dego);
    k_node<<<(NN + 255)/256, 256, 0, stream>>>(h, dego, degi, nsrc, ndst, out_w, xn0);

    // ---- layer 0 ----
    k_agg0<<<NN/2, 64, 0, stream>>>(xn0, offsets, degi, csr, aggB);
    k_gemm_mfma<32,128,true,true,false><<<GGRID, 256, 0, stream>>>(aggB, wt, b0, ndst, bufA, spart + 0*NPAGE*256);
    k_bnfin<<<1, 128, 0, stream>>>(spart + 0*NPAGE*256, stats + 0*512, g0, bt0);
    k_bnapply_bf<<<(NN*64 + 255)/256, 256, 0, stream>>>((unsigned*)bufA, stats + 0*512, nsrc, bufC);

    // ---- layer 1 ----
    k_agg_bf<<<NN, 64, 0, stream>>>(bufC, offsets, degi, csr, (unsigned*)aggB);
    k_gemm_mfma<128,128,true,true,false><<<GGRID, 256, 0, stream>>>(aggB, wt + 4096, b1, ndst, bufA, spart + 1*NPAGE*256);
    k_bnfin<<<1, 128, 0, stream>>>(spart + 1*NPAGE*256, stats + 1*512, g1, bt1);
    k_bnapply_bf<<<(NN*64 + 255)/256, 256, 0, stream>>>((unsigned*)bufA, stats + 1*512, nsrc, bufC);

    // ---- layer 2 ----
    k_agg_bf<<<NN, 64, 0, stream>>>(bufC, offsets, degi, csr, (unsigned*)aggB);
    k_gemm_mfma<128,128,true,true,false><<<GGRID, 256, 0, stream>>>(aggB, wt + 20480, b2, ndst, bufA, spart + 2*NPAGE*256);
    k_bnfin<<<1, 128, 0, stream>>>(spart + 2*NPAGE*256, stats + 2*512, g2, bt2);
    k_bnapply_bf<<<(NN*64 + 255)/256, 256, 0, stream>>>((unsigned*)bufA, stats + 2*512, nullptr, bufC);

    // ---- FC: out = x @ wfc + bfc ----
    k_gemm_mfma<128,64,false,false,true><<<GGRID, 256, 0, stream>>>((unsigned short*)bufC, wt + 36864, bfc,
                                                                    nullptr, out, nullptr);
}